// Round 3
// baseline (218.935 us; speedup 1.0000x reference)
//
#include <hip/hip_runtime.h>
#include <hip/hip_bf16.h>
#include <math.h>

#define BB 4
#define NN 512
#define TT 24
#define NXF 8
#define HH 64
#define PRED 12
#define MM (BB*NN)   // 2048

typedef __hip_bfloat16 bf16;

// ---------------- workspace arena layout (float offsets) ----------------
#define OFF_XF      0          // 393216
#define OFF_WFC     393216     // 512
#define OFF_BFC     393728     // 64
#define OFF_W1      393792     // 4096
#define OFF_AL1     397888     // 64
#define OFF_AR1     397952     // 64
#define OFF_BIAS1   398016     // 64
#define OFF_W2      398080     // 4096
#define OFF_AL2     402176     // 64
#define OFF_AR2     402240     // 64
#define OFF_BIAS2   402304     // 64
#define OFF_WIH     402368     // 16384
#define OFF_WHH     418752     // 16384
#define OFF_BIH     435136     // 256
#define OFF_BHH     435392     // 256
#define OFF_GL      435648     // 64
#define OFF_BL      435712     // 64
#define OFF_GG      435776     // 64
#define OFF_BG      435840     // 64
#define OFF_WD      435904     // 768
#define OFF_BD      436672     // 12 (pad 16)
#define OFF_WCOMB   436688     // 2048  (8 x 256, [f*256+g])
#define OFF_BCOMB   438736     // 256
#define OFF_WG1     438992     // 512   (8 x 64, [f*64+h])
#define OFF_BG1     439504     // 64
#define OFF_HBUF    439568     // 131072
#define OFF_G1      570640     // 131072
#define OFF_G2      701712     // 131072
#define OFF_HL      832784     // 131072
#define OFF_EL      963856     // 2048
#define OFF_ER      965904     // 2048
#define OFF_FLAG    967952     // 16 (int flag at [0])
#define OFF_MASK    967968     // mask bytes start here: 262144 B
// total ws usage ~ 4.14 MB

__device__ inline float b2f(bf16 v){ return __bfloat162float(v); }
__device__ inline float sigm(float x){ return 1.f / (1.f + __expf(-x)); }
__device__ inline float gelu_exact(float x){ return 0.5f * x * (1.f + erff(x * 0.70710678118654752440f)); }

// ---------------- dtype detect: are float inputs f32 or bf16? ----------------
__global__ void detect_kernel(const void* wfc, int* flag){
    const int t = threadIdx.x;
    const unsigned short* p = (const unsigned short*)wfc;
    bool bad = false;
    for (int i = t; i < 512; i += 256){
        float v = __uint_as_float(((unsigned)p[i]) << 16);
        if (!(fabsf(v) < 1e3f)) bad = true;   // NaN also lands here
    }
    unsigned long long m = __ballot(bad);
    if (t == 0) *flag = (m != 0ULL) ? 1 : 0;   // 1 => inputs are float32
}

__device__ inline float ldin(const void* p, int i, int isf32){
    return isf32 ? ((const float*)p)[i]
                 : __bfloat162float(((const bf16*)p)[i]);
}

// ---------------- convert x ----------------
__global__ __launch_bounds__(256) void convert_x_kernel(const void* x, const int* flag, float* arena){
    const int isf = *flag;
    int i = blockIdx.x * 256 + threadIdx.x;   // 1536 blocks * 256 = 393216
    arena[OFF_XF + i] = ldin(x, i, isf);
}

// ---------------- convert the 20 weight arrays ----------------
struct WDesc { const void* src[20]; int dst[20]; int n[20]; };

__global__ __launch_bounds__(256) void convert_w_kernel(WDesc d, const int* flag, float* arena){
    const int isf = *flag;
    const int a = blockIdx.y;
    const int i = blockIdx.x * 256 + threadIdx.x;
    if (i < d.n[a]) arena[d.dst[a] + i] = ldin(d.src[a], i, isf);
}

// ---------------- precompute folded weights ----------------
__global__ __launch_bounds__(256) void precomp_kernel(float* ws){
    const int i = blockIdx.x * 256 + threadIdx.x;
    const float* Wfc = ws + OFF_WFC;
    const float* bfc = ws + OFF_BFC;
    const float* W1  = ws + OFF_W1;
    const float* Wih = ws + OFF_WIH;
    if (i < 2048){
        int f = i >> 8, g = i & 255;
        float a = 0.f;
        #pragma unroll
        for (int k = 0; k < HH; ++k) a += Wfc[f*HH+k] * Wih[g*HH+k];
        ws[OFF_WCOMB + f*256 + g] = a;
    } else if (i < 2304){
        int g = i - 2048;
        float a = ws[OFF_BIH + g] + ws[OFF_BHH + g];
        #pragma unroll
        for (int k = 0; k < HH; ++k) a += bfc[k] * Wih[g*HH+k];
        ws[OFF_BCOMB + g] = a;
    } else if (i < 2816){
        int j = i - 2304;
        int f = j >> 6, h = j & 63;
        float a = 0.f;
        #pragma unroll
        for (int k = 0; k < HH; ++k) a += Wfc[f*HH+k] * W1[k*HH+h];
        ws[OFF_WG1 + f*HH + h] = a;
    } else if (i < 2880){
        int h = i - 2816;
        float a = 0.f;
        #pragma unroll
        for (int k = 0; k < HH; ++k) a += bfc[k] * W1[k*HH+h];
        ws[OFF_BG1 + h] = a;
    }
}

// ---------------- mask build ----------------
__global__ void mask_zero_kernel(uint4* mask16){
    int i = blockIdx.x * 256 + threadIdx.x;   // 64*256 = 16384 = 262144/16
    mask16[i] = make_uint4(0,0,0,0);
}

__global__ void mask_scatter_kernel(const int* ei, int E, unsigned char* mask){
    int e = blockIdx.x * 256 + threadIdx.x;
    if (e < E){
        int s = ei[e];
        int d = ei[E + e];
        mask[s * NN + d] = 1;
    }
}

// ---------------- GAT layer-1 pre: H = x(last)@Wg1 + bg1 ; el,er ----------------
__global__ __launch_bounds__(256) void gatpre8_kernel(const float* __restrict__ ws){
    float* wsm = (float*)ws;
    const float* xf  = ws + OFF_XF;
    const float* Wg1 = ws + OFF_WG1;
    const float* bg1 = ws + OFF_BG1;
    const float* al  = ws + OFF_AL1;
    const float* ar  = ws + OFF_AR1;
    float* Hout = wsm + OFF_HBUF;
    float* el   = wsm + OFF_EL;
    float* er   = wsm + OFF_ER;

    __shared__ float sw[NXF * HH];
    __shared__ float sal[HH], sar[HH];
    __shared__ float sx[4][NXF];
    const int t = threadIdx.x;
    const int r = t >> 6, h = t & 63;
    sw[t]       = Wg1[t];
    sw[256 + t] = Wg1[256 + t];
    if (t < 64) sal[t] = al[t];
    else if (t < 128) sar[t - 64] = ar[t - 64];
    if (t < 32){
        int rr = t >> 3, f = t & 7;
        sx[rr][f] = xf[((size_t)(blockIdx.x * 4 + rr) * TT + (TT - 1)) * NXF + f];
    }
    __syncthreads();
    const int m = blockIdx.x * 4 + r;
    float acc = bg1[h];
    #pragma unroll
    for (int f = 0; f < NXF; ++f) acc += sx[r][f] * sw[f * HH + h];
    Hout[(size_t)m * HH + h] = acc;
    float v1 = acc * sal[h];
    float v2 = acc * sar[h];
    #pragma unroll
    for (int o = 32; o; o >>= 1){
        v1 += __shfl_xor(v1, o);
        v2 += __shfl_xor(v2, o);
    }
    if (h == 0){ el[m] = v1; er[m] = v2; }
}

// ---------------- GAT layer-2 pre: H = g1 @ W2 ; el,er ----------------
__global__ __launch_bounds__(256) void gatpre64_kernel(const float* __restrict__ ws){
    float* wsm = (float*)ws;
    const float* Xin = ws + OFF_G1;
    const float* W   = ws + OFF_W2;
    const float* al  = ws + OFF_AL2;
    const float* ar  = ws + OFF_AR2;
    float* Hout = wsm + OFF_HBUF;
    float* el   = wsm + OFF_EL;
    float* er   = wsm + OFF_ER;

    __shared__ float sw[HH * HH];
    __shared__ float sal[HH], sar[HH];
    __shared__ float sx[4][HH];
    const int t = threadIdx.x;
    const int r = t >> 6, h = t & 63;
    #pragma unroll
    for (int i = 0; i < 16; ++i) sw[t + i * 256] = W[t + i * 256];
    if (t < 64) sal[t] = al[t];
    else if (t < 128) sar[t - 64] = ar[t - 64];
    const int m = blockIdx.x * 4 + r;
    sx[r][h] = Xin[(size_t)m * HH + h];
    __syncthreads();
    float acc = 0.f;
    #pragma unroll
    for (int f = 0; f < HH; ++f) acc += sx[r][f] * sw[f * HH + h];
    Hout[(size_t)m * HH + h] = acc;
    float v1 = acc * sal[h];
    float v2 = acc * sar[h];
    #pragma unroll
    for (int o = 32; o; o >>= 1){
        v1 += __shfl_xor(v1, o);
        v2 += __shfl_xor(v2, o);
    }
    if (h == 0){ el[m] = v1; er[m] = v2; }
}

// ---------------- GAT attention + aggregate + GELU ----------------
__global__ __launch_bounds__(256) void gat_attn_kernel(const float* __restrict__ ws,
                                                       int biasOff, int outOff){
    float* wsm = (float*)ws;
    const float* Hbuf = ws + OFF_HBUF;
    const float* el   = ws + OFF_EL;
    const float* er   = ws + OFF_ER;
    const float* bias = ws + biasOff;
    const unsigned char* mask = (const unsigned char*)(ws + OFF_MASK);
    float* gout = wsm + outOff;

    __shared__ float alpha[16][NN];
    const int t = threadIdx.x;
    const int b = blockIdx.x >> 5;           // 32 blocks per batch
    const int m0 = (blockIdx.x & 31) * 16;   // local row base
    const int w = t >> 6, l = t & 63;

    // phase A: softmax rows (each wave does 4 rows)
    for (int q = 0; q < 4; ++q){
        const int i = w * 4 + q;
        const int mloc = m0 + i;
        const float elv = el[b * NN + mloc];
        float e[8]; bool mk[8];
        float mx = -1e30f;
        #pragma unroll
        for (int j = 0; j < 8; ++j){
            int n = l + j * 64;
            float ev = elv + er[b * NN + n];
            ev = ev >= 0.f ? ev : 0.2f * ev;
            mk[j] = mask[mloc * NN + n] != 0;
            e[j] = ev;
            if (mk[j]) mx = fmaxf(mx, ev);
        }
        #pragma unroll
        for (int o = 32; o; o >>= 1) mx = fmaxf(mx, __shfl_xor(mx, o));
        float s = 0.f, p[8];
        #pragma unroll
        for (int j = 0; j < 8; ++j){
            p[j] = mk[j] ? __expf(e[j] - mx) : 0.f;
            s += p[j];
        }
        #pragma unroll
        for (int o = 32; o; o >>= 1) s += __shfl_xor(s, o);
        const float inv = 1.f / s;
        #pragma unroll
        for (int j = 0; j < 8; ++j) alpha[i][l + j * 64] = p[j] * inv;
    }
    __syncthreads();

    // phase B: out[i][h] = sum_n alpha[i][n] * H[b,n,h]
    const int h = t & 63, rg = t >> 6;
    float a0 = 0.f, a1 = 0.f, a2 = 0.f, a3 = 0.f;
    const float* Hb = Hbuf + (size_t)b * NN * HH + h;
    for (int n = 0; n < NN; ++n){
        float hv = Hb[(size_t)n * HH];
        a0 += alpha[rg     ][n] * hv;
        a1 += alpha[rg + 4 ][n] * hv;
        a2 += alpha[rg + 8 ][n] * hv;
        a3 += alpha[rg + 12][n] * hv;
    }
    const float bv = bias[h];
    const size_t base = (size_t)(b * NN + m0) * HH + h;
    gout[base + (size_t)(rg     ) * HH] = gelu_exact(a0 + bv);
    gout[base + (size_t)(rg + 4 ) * HH] = gelu_exact(a1 + bv);
    gout[base + (size_t)(rg + 8 ) * HH] = gelu_exact(a2 + bv);
    gout[base + (size_t)(rg + 12) * HH] = gelu_exact(a3 + bv);
}

// ---------------- LSTM (FC folded in): 4 rows/block ----------------
__global__ __launch_bounds__(256) void lstm_kernel(const float* __restrict__ ws){
    float* wsm = (float*)ws;
    const float* xf    = ws + OFF_XF;
    const float* Wcomb = ws + OFF_WCOMB;
    const float* bcomb = ws + OFF_BCOMB;
    const float* Whh   = ws + OFF_WHH;
    float* hlast = wsm + OFF_HL;

    __shared__ __align__(16) float hs[4][HH];
    __shared__ float cs[4][HH];
    __shared__ float gs[4][4 * HH];
    __shared__ float xs8[4][NXF];
    const int t = threadIdx.x;            // gate index 0..255
    const int m0 = blockIdx.x * 4;
    const int r = t >> 6, k = t & 63;

    float whh[HH], wc[NXF];
    {
        const float4* ph = (const float4*)(Whh + (size_t)t * HH);
        #pragma unroll
        for (int j = 0; j < 16; ++j){
            float4 u = ph[j];
            whh[j*4+0] = u.x; whh[j*4+1] = u.y; whh[j*4+2] = u.z; whh[j*4+3] = u.w;
        }
        #pragma unroll
        for (int f = 0; f < NXF; ++f) wc[f] = Wcomb[f * 256 + t];
    }
    const float bsum = bcomb[t];

    hs[r][k] = 0.f;
    cs[r][k] = 0.f;
    __syncthreads();

    for (int st = 0; st < TT; ++st){
        if (t < 32){
            int rr = t >> 3, f = t & 7;
            xs8[rr][f] = xf[((size_t)(m0 + rr) * TT + st) * NXF + f];
        }
        __syncthreads();
        #pragma unroll
        for (int r2 = 0; r2 < 4; ++r2){
            float a = bsum;
            #pragma unroll
            for (int f = 0; f < NXF; ++f) a += wc[f] * xs8[r2][f];
            const float4* hp = (const float4*)hs[r2];
            #pragma unroll
            for (int k4 = 0; k4 < 16; ++k4){
                float4 hv = hp[k4];
                a += whh[k4*4+0]*hv.x + whh[k4*4+1]*hv.y + whh[k4*4+2]*hv.z + whh[k4*4+3]*hv.w;
            }
            gs[r2][t] = a;
        }
        __syncthreads();
        {
            float iv = gs[r][k];
            float fv = gs[r][64 + k];
            float gv = gs[r][128 + k];
            float ov = gs[r][192 + k];
            float c = sigm(fv) * cs[r][k] + sigm(iv) * tanhf(gv);
            cs[r][k] = c;
            hs[r][k] = sigm(ov) * tanhf(c);
        }
        __syncthreads();
    }
    hlast[(size_t)(m0 + r) * HH + k] = hs[r][k];
}

// ---------------- final: LN(g2)+LN(l) then @ W_d + b_d (float32 out) ----------------
__global__ __launch_bounds__(256) void final_kernel(const float* __restrict__ ws,
                                                    float* __restrict__ out){
    const float* g2 = ws + OFF_G2;
    const float* hl = ws + OFF_HL;
    const float* g_l = ws + OFF_GL;
    const float* b_l = ws + OFF_BL;
    const float* g_g = ws + OFF_GG;
    const float* b_g = ws + OFF_BG;
    const float* W_d = ws + OFF_WD;
    const float* b_d = ws + OFF_BD;

    __shared__ float sbuf[4][HH];
    const int t = threadIdx.x;
    const int r = t >> 6, h = t & 63;
    const int m = blockIdx.x * 4 + r;
    float gv = g2[(size_t)m * HH + h];
    float lv = hl[(size_t)m * HH + h];

    float s1 = gv;
    #pragma unroll
    for (int o = 32; o; o >>= 1) s1 += __shfl_xor(s1, o);
    float mug = s1 * (1.f / 64.f);
    float dg = gv - mug;
    float v1 = dg * dg;
    #pragma unroll
    for (int o = 32; o; o >>= 1) v1 += __shfl_xor(v1, o);
    float lng = dg * rsqrtf(v1 * (1.f / 64.f) + 1e-5f) * g_g[h] + b_g[h];

    float s2 = lv;
    #pragma unroll
    for (int o = 32; o; o >>= 1) s2 += __shfl_xor(s2, o);
    float mul = s2 * (1.f / 64.f);
    float dl = lv - mul;
    float v2 = dl * dl;
    #pragma unroll
    for (int o = 32; o; o >>= 1) v2 += __shfl_xor(v2, o);
    float lnl = dl * rsqrtf(v2 * (1.f / 64.f) + 1e-5f) * g_l[h] + b_l[h];

    sbuf[r][h] = lng + lnl;
    __syncthreads();
    if (t < 48){
        int rr = t / 12, p = t % 12;
        float acc = b_d[p];
        #pragma unroll
        for (int k = 0; k < HH; ++k) acc += sbuf[rr][k] * W_d[k * PRED + p];
        out[(size_t)(blockIdx.x * 4 + rr) * PRED + p] = acc;
    }
}

extern "C" void kernel_launch(void* const* d_in, const int* in_sizes, int n_in,
                              void* d_out, int out_size, void* d_ws, size_t ws_size,
                              hipStream_t stream){
    const int* ei = (const int*)d_in[1];
    float* ws = (float*)d_ws;
    int* flag = (int*)(ws + OFF_FLAG);
    unsigned char* mask = (unsigned char*)(ws + OFF_MASK);

    const int E = in_sizes[1] / 2;   // 8704

    // 1. dtype detect (reads W_fc)
    detect_kernel<<<1, 256, 0, stream>>>(d_in[2], flag);

    // 2. convert all float inputs to fp32 arena
    convert_x_kernel<<<MM * TT * NXF / 256, 256, 0, stream>>>(d_in[0], flag, ws);
    {
        WDesc d;
        const int srcIdx[20] = {2,3,4,5,6,7,8,9,10,11,12,13,14,15,16,17,18,19,20,21};
        const int dsts[20] = {OFF_WFC,OFF_BFC,OFF_W1,OFF_AL1,OFF_AR1,OFF_BIAS1,
                              OFF_W2,OFF_AL2,OFF_AR2,OFF_BIAS2,
                              OFF_WIH,OFF_WHH,OFF_BIH,OFF_BHH,
                              OFF_GL,OFF_BL,OFF_GG,OFF_BG,OFF_WD,OFF_BD};
        for (int a = 0; a < 20; ++a){
            d.src[a] = d_in[srcIdx[a]];
            d.dst[a] = dsts[a];
            d.n[a]   = in_sizes[srcIdx[a]];
        }
        dim3 grid((16384 + 255) / 256, 20);
        convert_w_kernel<<<grid, 256, 0, stream>>>(d, flag, ws);
    }

    // 3. mask
    mask_zero_kernel<<<64, 256, 0, stream>>>((uint4*)mask);
    mask_scatter_kernel<<<(E + 255) / 256, 256, 0, stream>>>(ei, E, mask);

    // 4. folded weights
    precomp_kernel<<<12, 256, 0, stream>>>(ws);

    // 5. GAT layer 1 (last timestep only)
    gatpre8_kernel<<<MM / 4, 256, 0, stream>>>(ws);
    gat_attn_kernel<<<BB * (NN / 16), 256, 0, stream>>>(ws, OFF_BIAS1, OFF_G1);

    // 6. GAT layer 2
    gatpre64_kernel<<<MM / 4, 256, 0, stream>>>(ws);
    gat_attn_kernel<<<BB * (NN / 16), 256, 0, stream>>>(ws, OFF_BIAS2, OFF_G2);

    // 7. LSTM (FC folded in)
    lstm_kernel<<<MM / 4, 256, 0, stream>>>(ws);

    // 8. layernorms + decode
    final_kernel<<<MM / 4, 256, 0, stream>>>(ws, (float*)d_out);
}

// Round 4
// 195.747 us; speedup vs baseline: 1.1185x; 1.1185x over previous
//
#include <hip/hip_runtime.h>
#include <hip/hip_bf16.h>
#include <math.h>

#define BB 4
#define NN 512
#define TT 24
#define NXF 8
#define HH 64
#define PRED 12
#define MM (BB*NN)   // 2048

typedef __attribute__((ext_vector_type(8))) short short8;
typedef __attribute__((ext_vector_type(4))) float f32x4;

// ---- workspace layout (float offsets) ----
#define WS_HBUF 0         // 131072  H1
#define WS_H2   131072    // 131072  H2
#define WS_G2   262144    // 131072  g2
#define WS_EL   393216    // 2048
#define WS_ER   395264    // 2048
#define WS_EL2  397312    // 2048
#define WS_ER2  399360    // 2048

__device__ inline float sigm(float x){ return 1.f/(1.f+__expf(-x)); }
__device__ inline float tanh_fast(float x){ float e=__expf(2.f*x); return 1.f - 2.f/(e+1.f); }
__device__ inline float gelu_exact(float x){ return 0.5f*x*(1.f+erff(x*0.70710678118654752440f)); }
__device__ inline unsigned short f2bu(float f){           // RNE f32 -> bf16 bits
    unsigned b=__float_as_uint(f);
    return (unsigned short)((b + 0x7FFFu + ((b>>16)&1u))>>16);
}
__device__ inline float bu2f(unsigned short u){ return __uint_as_float(((unsigned)u)<<16); }

// =============== K1: H1 = (x_last @ Wfc + bfc) @ W1 ; el1, er1 ===============
__global__ __launch_bounds__(256,2) void gat1pre_kernel(
    const float* __restrict__ x, const float* __restrict__ Wfc, const float* __restrict__ bfc,
    const float* __restrict__ W1, const float* __restrict__ al1, const float* __restrict__ ar1,
    float* __restrict__ Hbuf, float* __restrict__ el, float* __restrict__ er)
{
    __shared__ float sw1[HH*HH];
    __shared__ float swfc[NXF*HH];
    __shared__ float sb[HH], sal[HH], sar[HH];
    __shared__ float sxh[4][68];
    __shared__ float sx[4][NXF];
    const int t = threadIdx.x;
    const int r = t >> 6, h = t & 63;
    #pragma unroll
    for (int i = 0; i < 16; ++i) sw1[t + 256*i] = W1[t + 256*i];
    swfc[t] = Wfc[t];
    swfc[t+256] = Wfc[t+256];
    if (t < 64) sb[t] = bfc[t];
    else if (t < 128) sal[t-64] = al1[t-64];
    else if (t < 192) sar[t-128] = ar1[t-128];
    if (t < 32){
        int rr = t >> 3, f = t & 7;
        sx[rr][f] = x[(size_t)(blockIdx.x*4 + rr)*(TT*NXF) + (TT-1)*NXF + f];
    }
    __syncthreads();
    float xh = sb[h];
    #pragma unroll
    for (int f = 0; f < NXF; ++f) xh += sx[r][f]*swfc[f*HH + h];
    sxh[r][h] = xh;
    __syncthreads();
    float acc = 0.f;
    const float4* xr = (const float4*)&sxh[r][0];
    #pragma unroll
    for (int k4 = 0; k4 < 16; ++k4){
        float4 xv = xr[k4];
        acc += xv.x*sw1[(4*k4+0)*HH+h] + xv.y*sw1[(4*k4+1)*HH+h]
             + xv.z*sw1[(4*k4+2)*HH+h] + xv.w*sw1[(4*k4+3)*HH+h];
    }
    const int m = blockIdx.x*4 + r;
    Hbuf[(size_t)m*HH + h] = acc;
    float v1 = acc*sal[h], v2 = acc*sar[h];
    #pragma unroll
    for (int o = 32; o; o >>= 1){ v1 += __shfl_xor(v1,o); v2 += __shfl_xor(v2,o); }
    if (h == 0){ el[m] = v1; er[m] = v2; }
}

// =============== K2: attn layer1 (mask built in-LDS) + fused GAT2-pre ===============
__global__ __launch_bounds__(256,2) void attn_fuse_kernel(
    const float* __restrict__ Hbuf, const float* __restrict__ el_in, const float* __restrict__ er_in,
    const int* __restrict__ ei, int E,
    const float* __restrict__ bias1,
    const float* __restrict__ W2, const float* __restrict__ al2, const float* __restrict__ ar2,
    float* __restrict__ H2, float* __restrict__ el2, float* __restrict__ er2)
{
    __shared__ unsigned smask[16][16];
    __shared__ float er_s[NN];
    __shared__ float alpha[16][NN];
    __shared__ float sw2[HH*HH];
    __shared__ float xh2[16][68];
    __shared__ float sal[HH], sar[HH];

    const int t = threadIdx.x;
    const int b = blockIdx.x >> 5;
    const int m0 = (blockIdx.x & 31) * 16;
    const int l = t & 63, w = t >> 6;

    #pragma unroll
    for (int i = 0; i < 16; ++i) sw2[t + 256*i] = W2[t + 256*i];
    if (t < 64) sal[t] = al2[t]; else if (t < 128) sar[t-64] = ar2[t-64];
    ((unsigned*)smask)[t] = 0;
    er_s[t] = er_in[b*NN + t];
    er_s[t+256] = er_in[b*NN + t + 256];
    __syncthreads();
    for (int e = t; e < E; e += 256){
        int s = ei[e];
        unsigned rl = (unsigned)(s - m0);
        if (rl < 16u){
            int d = ei[E + e];
            atomicOr(&smask[rl][d>>5], 1u << (d & 31));
        }
    }
    __syncthreads();
    // phase A: masked softmax rows
    for (int q = 0; q < 4; ++q){
        const int i = w*4 + q;
        const float elv = el_in[b*NN + m0 + i];
        float e8[8]; unsigned mk = 0; float mx = -1e30f;
        #pragma unroll
        for (int j = 0; j < 8; ++j){
            int n = l + 64*j;
            float ev = elv + er_s[n];
            ev = ev >= 0.f ? ev : 0.2f*ev;
            unsigned mb = (smask[i][(l>>5) + 2*j] >> (l & 31)) & 1u;
            e8[j] = ev;
            if (mb){ mk |= (1u<<j); mx = fmaxf(mx, ev); }
        }
        #pragma unroll
        for (int o = 32; o; o >>= 1) mx = fmaxf(mx, __shfl_xor(mx, o));
        float s = 0.f;
        #pragma unroll
        for (int j = 0; j < 8; ++j){
            float p = ((mk>>j) & 1u) ? __expf(e8[j]-mx) : 0.f;
            e8[j] = p; s += p;
        }
        #pragma unroll
        for (int o = 32; o; o >>= 1) s += __shfl_xor(s, o);
        const float inv = 1.f/s;
        #pragma unroll
        for (int j = 0; j < 8; ++j) alpha[i][l + 64*j] = e8[j]*inv;
    }
    __syncthreads();
    // phase B: aggregate + gelu -> xh2 (LDS only; g1 never hits global)
    const int h = l;
    float a0=0.f,a1=0.f,a2=0.f,a3=0.f;
    const float* Hb = Hbuf + (size_t)b*NN*HH + h;
    const float4* A0 = (const float4*)alpha[w];
    const float4* A1 = (const float4*)alpha[w+4];
    const float4* A2 = (const float4*)alpha[w+8];
    const float4* A3 = (const float4*)alpha[w+12];
    for (int g = 0; g < NN/4; ++g){
        float4 p0 = A0[g], p1 = A1[g], p2 = A2[g], p3 = A3[g];
        float h0 = Hb[(size_t)(4*g+0)*HH], h1 = Hb[(size_t)(4*g+1)*HH];
        float h2 = Hb[(size_t)(4*g+2)*HH], h3 = Hb[(size_t)(4*g+3)*HH];
        a0 += p0.x*h0 + p0.y*h1 + p0.z*h2 + p0.w*h3;
        a1 += p1.x*h0 + p1.y*h1 + p1.z*h2 + p1.w*h3;
        a2 += p2.x*h0 + p2.y*h1 + p2.z*h2 + p2.w*h3;
        a3 += p3.x*h0 + p3.y*h1 + p3.z*h2 + p3.w*h3;
    }
    const float bv = bias1[h];
    xh2[w   ][h] = gelu_exact(a0+bv);
    xh2[w+4 ][h] = gelu_exact(a1+bv);
    xh2[w+8 ][h] = gelu_exact(a2+bv);
    xh2[w+12][h] = gelu_exact(a3+bv);
    __syncthreads();
    // fused GAT2 pre: H2 = g1 @ W2 ; el2, er2
    for (int q = 0; q < 4; ++q){
        const int i = w + 4*q;
        float acc = 0.f;
        const float4* xr = (const float4*)&xh2[i][0];
        #pragma unroll
        for (int k4 = 0; k4 < 16; ++k4){
            float4 xv = xr[k4];
            acc += xv.x*sw2[(4*k4+0)*HH+h] + xv.y*sw2[(4*k4+1)*HH+h]
                 + xv.z*sw2[(4*k4+2)*HH+h] + xv.w*sw2[(4*k4+3)*HH+h];
        }
        const int m = b*NN + m0 + i;
        H2[(size_t)m*HH + h] = acc;
        float v1 = acc*sal[h], v2 = acc*sar[h];
        #pragma unroll
        for (int o = 32; o; o >>= 1){ v1 += __shfl_xor(v1,o); v2 += __shfl_xor(v2,o); }
        if (h == 0){ el2[m] = v1; er2[m] = v2; }
    }
}

// =============== K3: attn layer2 -> g2 ===============
__global__ __launch_bounds__(256,2) void attn2_kernel(
    const float* __restrict__ Hbuf, const float* __restrict__ el_in, const float* __restrict__ er_in,
    const int* __restrict__ ei, int E,
    const float* __restrict__ bias2, float* __restrict__ g2)
{
    __shared__ unsigned smask[16][16];
    __shared__ float er_s[NN];
    __shared__ float alpha[16][NN];
    const int t = threadIdx.x;
    const int b = blockIdx.x >> 5;
    const int m0 = (blockIdx.x & 31) * 16;
    const int l = t & 63, w = t >> 6;

    ((unsigned*)smask)[t] = 0;
    er_s[t] = er_in[b*NN + t];
    er_s[t+256] = er_in[b*NN + t + 256];
    __syncthreads();
    for (int e = t; e < E; e += 256){
        int s = ei[e];
        unsigned rl = (unsigned)(s - m0);
        if (rl < 16u){
            int d = ei[E + e];
            atomicOr(&smask[rl][d>>5], 1u << (d & 31));
        }
    }
    __syncthreads();
    for (int q = 0; q < 4; ++q){
        const int i = w*4 + q;
        const float elv = el_in[b*NN + m0 + i];
        float e8[8]; unsigned mk = 0; float mx = -1e30f;
        #pragma unroll
        for (int j = 0; j < 8; ++j){
            int n = l + 64*j;
            float ev = elv + er_s[n];
            ev = ev >= 0.f ? ev : 0.2f*ev;
            unsigned mb = (smask[i][(l>>5) + 2*j] >> (l & 31)) & 1u;
            e8[j] = ev;
            if (mb){ mk |= (1u<<j); mx = fmaxf(mx, ev); }
        }
        #pragma unroll
        for (int o = 32; o; o >>= 1) mx = fmaxf(mx, __shfl_xor(mx, o));
        float s = 0.f;
        #pragma unroll
        for (int j = 0; j < 8; ++j){
            float p = ((mk>>j) & 1u) ? __expf(e8[j]-mx) : 0.f;
            e8[j] = p; s += p;
        }
        #pragma unroll
        for (int o = 32; o; o >>= 1) s += __shfl_xor(s, o);
        const float inv = 1.f/s;
        #pragma unroll
        for (int j = 0; j < 8; ++j) alpha[i][l + 64*j] = e8[j]*inv;
    }
    __syncthreads();
    const int h = l;
    float a0=0.f,a1=0.f,a2=0.f,a3=0.f;
    const float* Hb = Hbuf + (size_t)b*NN*HH + h;
    const float4* A0 = (const float4*)alpha[w];
    const float4* A1 = (const float4*)alpha[w+4];
    const float4* A2 = (const float4*)alpha[w+8];
    const float4* A3 = (const float4*)alpha[w+12];
    for (int g = 0; g < NN/4; ++g){
        float4 p0 = A0[g], p1 = A1[g], p2 = A2[g], p3 = A3[g];
        float h0 = Hb[(size_t)(4*g+0)*HH], h1 = Hb[(size_t)(4*g+1)*HH];
        float h2 = Hb[(size_t)(4*g+2)*HH], h3 = Hb[(size_t)(4*g+3)*HH];
        a0 += p0.x*h0 + p0.y*h1 + p0.z*h2 + p0.w*h3;
        a1 += p1.x*h0 + p1.y*h1 + p1.z*h2 + p1.w*h3;
        a2 += p2.x*h0 + p2.y*h1 + p2.z*h2 + p2.w*h3;
        a3 += p3.x*h0 + p3.y*h1 + p3.z*h2 + p3.w*h3;
    }
    const float bv = bias2[h];
    const size_t base = (size_t)(b*NN + m0)*HH + h;
    g2[base + (size_t)(w   )*HH] = gelu_exact(a0+bv);
    g2[base + (size_t)(w+4 )*HH] = gelu_exact(a1+bv);
    g2[base + (size_t)(w+8 )*HH] = gelu_exact(a2+bv);
    g2[base + (size_t)(w+12)*HH] = gelu_exact(a3+bv);
}

// =============== K4: MFMA LSTM (FC folded) + LN + decode ===============
// block = 16 sequences. Per step: gates[16x256] = [h_hi|h_lo|x_pad] @ [W;W;Wcomb] via
// 4 waves x 4 gate-tiles x 5 mfma_f32_16x16x32_bf16. Wave w owns tiles {w,w+4,w+8,w+12}
// = (i,f,g,o) for gate-cols w*16+c. h carried hi/lo split-bf16, double-buffered LDS.
#define LHS 72   // h row stride (bf16), 64 + 8 pad
#define LXS 40   // x row stride (bf16), 32 + 8 pad
__global__ __launch_bounds__(256,2) void lstm_final_kernel(
    const float* __restrict__ x,
    const float* __restrict__ Wfc, const float* __restrict__ bfc,
    const float* __restrict__ Wih, const float* __restrict__ Whh,
    const float* __restrict__ bih, const float* __restrict__ bhh,
    const float* __restrict__ g2,
    const float* __restrict__ g_l, const float* __restrict__ b_l,
    const float* __restrict__ g_g, const float* __restrict__ b_g,
    const float* __restrict__ W_d, const float* __restrict__ b_d,
    float* __restrict__ out)
{
    __shared__ __align__(16) unsigned short hbi[2][16*LHS];
    __shared__ __align__(16) unsigned short hlo[2][16*LHS];
    __shared__ __align__(16) unsigned short xls[TT*16*LXS];
    __shared__ float wfcT[64*8];     // [k][f]
    __shared__ float sbfc[64];
    __shared__ float wcomb[8*256];   // [f][g]; reused as h_final f32 in epilogue
    __shared__ float sbc[256];

    const int t = threadIdx.x;
    const int m0 = blockIdx.x * 16;
    const int lane = t & 63;
    const int w = t >> 6;
    const int quad = lane >> 4;
    const int c16 = lane & 15;

    // stage Wfc^T + bfc, zero h buf0 + x pads
    { int i = t;     wfcT[(i&63)*8 + (i>>6)] = Wfc[i]; }
    { int i = t+256; wfcT[(i&63)*8 + (i>>6)] = Wfc[i]; }
    if (t < 64) sbfc[t] = bfc[t];
    {
        unsigned* h0 = (unsigned*)hbi[0];
        unsigned* l0 = (unsigned*)hlo[0];
        for (int i = t; i < 16*LHS/2; i += 256){ h0[i] = 0u; l0[i] = 0u; }
        unsigned* xw = (unsigned*)xls;
        for (int i = t; i < TT*16*LXS/2; i += 256) xw[i] = 0u;
    }
    __syncthreads();
    // fill x (bf16) into padded LDS
    for (int i = t; i < 16*TT*NXF; i += 256){
        int r = i / (TT*NXF);
        int rem = i - r*(TT*NXF);
        int st = rem >> 3, f = rem & 7;
        xls[st*(16*LXS) + r*LXS + f] = f2bu(x[(size_t)(m0+r)*(TT*NXF) + rem]);
    }
    // fold FC into gate weights: wcomb[f][g] = sum_k Wfc[f][k] Wih[g][k]; bcomb
    {
        float accf[8] = {0,0,0,0,0,0,0,0};
        float accb = 0.f;
        for (int kk = 0; kk < 64; ++kk){
            float wv = Wih[t*64 + kk];
            accb += sbfc[kk]*wv;
            const float4* wf = (const float4*)&wfcT[kk*8];
            float4 u0 = wf[0], u1 = wf[1];
            accf[0]+=u0.x*wv; accf[1]+=u0.y*wv; accf[2]+=u0.z*wv; accf[3]+=u0.w*wv;
            accf[4]+=u1.x*wv; accf[5]+=u1.y*wv; accf[6]+=u1.z*wv; accf[7]+=u1.w*wv;
        }
        #pragma unroll
        for (int f = 0; f < 8; ++f) wcomb[f*256 + t] = accf[f];
        sbc[t] = accb + bih[t] + bhh[t];
    }
    __syncthreads();
    // build B-fragments (registers): B[k][n] -> lane n=c16, k=quad*8+j
    short8 bw[4][2]; short8 bx[4]; float bc[4];
    #pragma unroll
    for (int tt = 0; tt < 4; ++tt){
        const int ng = (w + 4*tt)*16 + c16;   // gate index
        bc[tt] = sbc[ng];
        #pragma unroll
        for (int ks = 0; ks < 2; ++ks){
            const float* wp = &Whh[ng*64 + ks*32 + quad*8];
            short8 v;
            #pragma unroll
            for (int j = 0; j < 8; ++j) v[j] = (short)f2bu(wp[j]);
            bw[tt][ks] = v;
        }
        short8 vx;
        #pragma unroll
        for (int j = 0; j < 8; ++j) vx[j] = (quad==0) ? (short)f2bu(wcomb[j*256 + ng]) : (short)0;
        bx[tt] = vx;
    }
    float cst[4] = {0,0,0,0};
    float hf[4]  = {0,0,0,0};

    for (int st = 0; st < TT; ++st){
        const int p = st & 1;
        const unsigned short* hb = hbi[p];
        const unsigned short* hl_ = hlo[p];
        // A-fragments: A[m=c16][k=quad*8+j]
        short8 ahi0 = *(const short8*)&hb[c16*LHS + quad*8];
        short8 ahi1 = *(const short8*)&hb[c16*LHS + 32 + quad*8];
        short8 alo0 = *(const short8*)&hl_[c16*LHS + quad*8];
        short8 alo1 = *(const short8*)&hl_[c16*LHS + 32 + quad*8];
        short8 ax   = *(const short8*)&xls[st*(16*LXS) + c16*LXS + quad*8];
        f32x4 acc[4];
        #pragma unroll
        for (int tt = 0; tt < 4; ++tt){
            f32x4 a = {bc[tt], bc[tt], bc[tt], bc[tt]};
            a = __builtin_amdgcn_mfma_f32_16x16x32_bf16(ax,   bx[tt],    a, 0,0,0);
            a = __builtin_amdgcn_mfma_f32_16x16x32_bf16(ahi0, bw[tt][0], a, 0,0,0);
            a = __builtin_amdgcn_mfma_f32_16x16x32_bf16(ahi1, bw[tt][1], a, 0,0,0);
            a = __builtin_amdgcn_mfma_f32_16x16x32_bf16(alo0, bw[tt][0], a, 0,0,0);
            a = __builtin_amdgcn_mfma_f32_16x16x32_bf16(alo1, bw[tt][1], a, 0,0,0);
            acc[tt] = a;
        }
        unsigned short* ho = hbi[p^1];
        unsigned short* lo_o = hlo[p^1];
        #pragma unroll
        for (int reg = 0; reg < 4; ++reg){
            // C-layout: row = quad*4+reg, col(gate within 64) = w*16+c16
            float gi = acc[0][reg], gf = acc[1][reg], gg = acc[2][reg], go = acc[3][reg];
            float cn = sigm(gf)*cst[reg] + sigm(gi)*tanh_fast(gg);
            cst[reg] = cn;
            float hn = sigm(go)*tanh_fast(cn);
            hf[reg] = hn;
            unsigned short hu = f2bu(hn);
            float lov = hn - bu2f(hu);
            int addr = (quad*4+reg)*LHS + w*16 + c16;
            ho[addr] = hu;
            lo_o[addr] = f2bu(lov);
        }
        __syncthreads();
    }

    // epilogue: LN(g2)+LN(h) -> decode
    float* hfin = wcomb;   // reuse (4 KB of 8 KB)
    #pragma unroll
    for (int reg = 0; reg < 4; ++reg)
        hfin[(quad*4+reg)*HH + w*16 + c16] = hf[reg];
    __syncthreads();
    float* sdec = (float*)xls;  // reuse (4 KB of 30 KB)
    const int h = lane;
    for (int q = 0; q < 4; ++q){
        const int ml = w*4 + q;
        float lv = hfin[ml*HH + h];
        float gv = g2[(size_t)(m0+ml)*HH + h];

        float s1 = gv;
        #pragma unroll
        for (int o = 32; o; o >>= 1) s1 += __shfl_xor(s1, o);
        float dg = gv - s1*(1.f/64.f);
        float v1 = dg*dg;
        #pragma unroll
        for (int o = 32; o; o >>= 1) v1 += __shfl_xor(v1, o);
        float lng = dg*rsqrtf(v1*(1.f/64.f) + 1e-5f)*g_g[h] + b_g[h];

        float s2 = lv;
        #pragma unroll
        for (int o = 32; o; o >>= 1) s2 += __shfl_xor(s2, o);
        float dl = lv - s2*(1.f/64.f);
        float v2 = dl*dl;
        #pragma unroll
        for (int o = 32; o; o >>= 1) v2 += __shfl_xor(v2, o);
        float lnl = dl*rsqrtf(v2*(1.f/64.f) + 1e-5f)*g_l[h] + b_l[h];

        sdec[ml*HH + h] = lng + lnl;
    }
    __syncthreads();
    if (t < 16*PRED){
        int rr = t / PRED, pp = t - rr*PRED;
        float acc = b_d[pp];
        #pragma unroll
        for (int k = 0; k < HH; ++k) acc += sdec[rr*HH + k]*W_d[k*PRED + pp];
        out[(size_t)(m0+rr)*PRED + pp] = acc;
    }
}

extern "C" void kernel_launch(void* const* d_in, const int* in_sizes, int n_in,
                              void* d_out, int out_size, void* d_ws, size_t ws_size,
                              hipStream_t stream){
    const float* x    = (const float*)d_in[0];
    const int*   ei   = (const int*)  d_in[1];
    const float* Wfc  = (const float*)d_in[2];
    const float* bfc  = (const float*)d_in[3];
    const float* W1   = (const float*)d_in[4];
    const float* al1  = (const float*)d_in[5];
    const float* ar1  = (const float*)d_in[6];
    const float* bias1= (const float*)d_in[7];
    const float* W2   = (const float*)d_in[8];
    const float* al2  = (const float*)d_in[9];
    const float* ar2  = (const float*)d_in[10];
    const float* bias2= (const float*)d_in[11];
    const float* Wih  = (const float*)d_in[12];
    const float* Whh  = (const float*)d_in[13];
    const float* bih  = (const float*)d_in[14];
    const float* bhh  = (const float*)d_in[15];
    const float* g_l  = (const float*)d_in[16];
    const float* b_l  = (const float*)d_in[17];
    const float* g_g  = (const float*)d_in[18];
    const float* b_g  = (const float*)d_in[19];
    const float* W_d  = (const float*)d_in[20];
    const float* b_d  = (const float*)d_in[21];

    float* ws = (float*)d_ws;
    const int E = in_sizes[1] / 2;

    gat1pre_kernel<<<MM/4, 256, 0, stream>>>(x, Wfc, bfc, W1, al1, ar1,
                                             ws+WS_HBUF, ws+WS_EL, ws+WS_ER);
    attn_fuse_kernel<<<BB*(NN/16), 256, 0, stream>>>(ws+WS_HBUF, ws+WS_EL, ws+WS_ER,
                                                     ei, E, bias1, W2, al2, ar2,
                                                     ws+WS_H2, ws+WS_EL2, ws+WS_ER2);
    attn2_kernel<<<BB*(NN/16), 256, 0, stream>>>(ws+WS_H2, ws+WS_EL2, ws+WS_ER2,
                                                 ei, E, bias2, ws+WS_G2);
    lstm_final_kernel<<<MM/16, 256, 0, stream>>>(x, Wfc, bfc, Wih, Whh, bih, bhh,
                                                 ws+WS_G2, g_l, b_l, g_g, b_g, W_d, b_d,
                                                 (float*)d_out);
}

// Round 5
// 195.562 us; speedup vs baseline: 1.1195x; 1.0009x over previous
//
#include <hip/hip_runtime.h>
#include <hip/hip_bf16.h>
#include <math.h>

#define BB 4
#define NN 512
#define TT 24
#define NXF 8
#define HH 64
#define PRED 12
#define MM (BB*NN)   // 2048

typedef __attribute__((ext_vector_type(8))) short short8;
typedef __attribute__((ext_vector_type(4))) float f32x4;

// ---- workspace layout (float offsets) ----
#define WS_HBUF    0         // 131072  H1
#define WS_H2      131072    // 131072  H2
#define WS_G2      262144    // 131072  g2
#define WS_EL      393216    // 2048
#define WS_ER      395264    // 2048
#define WS_EL2     397312    // 2048
#define WS_ER2     399360    // 2048
#define WS_WCOMB   401408    // 2048 f32   [f][ng] = sum_k Wfc[f][k]*Wih[ng][k]
#define WS_BCOMB   403456    // 256  f32
#define WS_WHHFRAG 403712    // 16384 bf16 (= 8192 f32 slots), per-lane frag order

__device__ inline float sigm(float x){ return 1.f/(1.f+__expf(-x)); }
__device__ inline float tanh_fast(float x){ float e=__expf(2.f*x); return 1.f - 2.f/(e+1.f); }
__device__ inline float gelu_exact(float x){ return 0.5f*x*(1.f+erff(x*0.70710678118654752440f)); }
__device__ inline unsigned short f2bu(float f){           // RNE f32 -> bf16 bits
    unsigned b=__float_as_uint(f);
    return (unsigned short)((b + 0x7FFFu + ((b>>16)&1u))>>16);
}
__device__ inline float bu2f(unsigned short u){ return __uint_as_float(((unsigned)u)<<16); }

// =============== K1: H1 = (x_last @ Wfc + bfc) @ W1 ; el1, er1 ===============
// blocks [0,512): GAT1 pre. blocks [512,520): LSTM weight precomp (fold + frag-layout).
__global__ __launch_bounds__(256,2) void gat1pre_kernel(
    const float* __restrict__ x, const float* __restrict__ Wfc, const float* __restrict__ bfc,
    const float* __restrict__ W1, const float* __restrict__ al1, const float* __restrict__ ar1,
    const float* __restrict__ Wih, const float* __restrict__ Whh,
    const float* __restrict__ bih, const float* __restrict__ bhh,
    float* __restrict__ Hbuf, float* __restrict__ el, float* __restrict__ er,
    float* __restrict__ wcombG, float* __restrict__ bcombG,
    unsigned short* __restrict__ whhfrag)
{
    __shared__ float sw1[HH*HH];
    __shared__ float swfc[NXF*HH];
    __shared__ float sb[HH], sal[HH], sar[HH];
    __shared__ float sxh[4][68];
    __shared__ float sx[4][NXF];
    const int t = threadIdx.x;

    if (blockIdx.x >= 512){
        // ---- LSTM precomp ----
        const int f = blockIdx.x - 512;   // 0..7
        const int ng = t;                 // 0..255
        float accf = 0.f, accb = 0.f;
        const float* wr = Wih + ng*64;
        #pragma unroll
        for (int k = 0; k < 64; ++k){
            float wv = wr[k];
            accf += Wfc[f*64 + k] * wv;
            accb += bfc[k] * wv;
        }
        wcombG[f*256 + ng] = accf;
        if (f == 0) bcombG[ng] = accb + bih[ng] + bhh[ng];
        // Whh -> bf16 in per-lane fragment order:
        // o = F*512 + lane*8 + j ; F = (w*4+tt)*2+ks ; ng' = (w+4tt)*16 + (lane&15)
        #pragma unroll
        for (int u = 0; u < 8; ++u){
            int o = f*2048 + u*256 + t;
            int F  = o >> 9;
            int ln = (o >> 3) & 63;
            int j  = o & 7;
            int w_ = F >> 3, tt = (F >> 1) & 3, ks = F & 1;
            int q = ln >> 4, c = ln & 15;
            int ngx = (w_ + 4*tt)*16 + c;
            whhfrag[o] = f2bu(Whh[ngx*64 + ks*32 + q*8 + j]);
        }
        return;
    }

    const int r = t >> 6, h = t & 63;
    #pragma unroll
    for (int i = 0; i < 16; ++i) sw1[t + 256*i] = W1[t + 256*i];
    swfc[t] = Wfc[t];
    swfc[t+256] = Wfc[t+256];
    if (t < 64) sb[t] = bfc[t];
    else if (t < 128) sal[t-64] = al1[t-64];
    else if (t < 192) sar[t-128] = ar1[t-128];
    if (t < 32){
        int rr = t >> 3, f = t & 7;
        sx[rr][f] = x[(size_t)(blockIdx.x*4 + rr)*(TT*NXF) + (TT-1)*NXF + f];
    }
    __syncthreads();
    float xh = sb[h];
    #pragma unroll
    for (int f = 0; f < NXF; ++f) xh += sx[r][f]*swfc[f*HH + h];
    sxh[r][h] = xh;
    __syncthreads();
    float acc = 0.f;
    const float4* xr = (const float4*)&sxh[r][0];
    #pragma unroll
    for (int k4 = 0; k4 < 16; ++k4){
        float4 xv = xr[k4];
        acc += xv.x*sw1[(4*k4+0)*HH+h] + xv.y*sw1[(4*k4+1)*HH+h]
             + xv.z*sw1[(4*k4+2)*HH+h] + xv.w*sw1[(4*k4+3)*HH+h];
    }
    const int m = blockIdx.x*4 + r;
    Hbuf[(size_t)m*HH + h] = acc;
    float v1 = acc*sal[h], v2 = acc*sar[h];
    #pragma unroll
    for (int o = 32; o; o >>= 1){ v1 += __shfl_xor(v1,o); v2 += __shfl_xor(v2,o); }
    if (h == 0){ el[m] = v1; er[m] = v2; }
}

// =============== K2: attn layer1 (mask built in-LDS) + fused GAT2-pre ===============
__global__ __launch_bounds__(256,2) void attn_fuse_kernel(
    const float* __restrict__ Hbuf, const float* __restrict__ el_in, const float* __restrict__ er_in,
    const int* __restrict__ ei, int E,
    const float* __restrict__ bias1,
    const float* __restrict__ W2, const float* __restrict__ al2, const float* __restrict__ ar2,
    float* __restrict__ H2, float* __restrict__ el2, float* __restrict__ er2)
{
    __shared__ unsigned smask[16][16];
    __shared__ float er_s[NN];
    __shared__ float alpha[16][NN];
    __shared__ float sw2[HH*HH];
    __shared__ float xh2[16][68];
    __shared__ float sal[HH], sar[HH];

    const int t = threadIdx.x;
    const int b = blockIdx.x >> 5;
    const int m0 = (blockIdx.x & 31) * 16;
    const int l = t & 63, w = t >> 6;

    #pragma unroll
    for (int i = 0; i < 16; ++i) sw2[t + 256*i] = W2[t + 256*i];
    if (t < 64) sal[t] = al2[t]; else if (t < 128) sar[t-64] = ar2[t-64];
    ((unsigned*)smask)[t] = 0;
    er_s[t] = er_in[b*NN + t];
    er_s[t+256] = er_in[b*NN + t + 256];
    __syncthreads();
    for (int e = t; e < E; e += 256){
        int s = ei[e];
        unsigned rl = (unsigned)(s - m0);
        if (rl < 16u){
            int d = ei[E + e];
            atomicOr(&smask[rl][d>>5], 1u << (d & 31));
        }
    }
    __syncthreads();
    // phase A: masked softmax rows
    for (int q = 0; q < 4; ++q){
        const int i = w*4 + q;
        const float elv = el_in[b*NN + m0 + i];
        float e8[8]; unsigned mk = 0; float mx = -1e30f;
        #pragma unroll
        for (int j = 0; j < 8; ++j){
            int n = l + 64*j;
            float ev = elv + er_s[n];
            ev = ev >= 0.f ? ev : 0.2f*ev;
            unsigned mb = (smask[i][(l>>5) + 2*j] >> (l & 31)) & 1u;
            e8[j] = ev;
            if (mb){ mk |= (1u<<j); mx = fmaxf(mx, ev); }
        }
        #pragma unroll
        for (int o = 32; o; o >>= 1) mx = fmaxf(mx, __shfl_xor(mx, o));
        float s = 0.f;
        #pragma unroll
        for (int j = 0; j < 8; ++j){
            float p = ((mk>>j) & 1u) ? __expf(e8[j]-mx) : 0.f;
            e8[j] = p; s += p;
        }
        #pragma unroll
        for (int o = 32; o; o >>= 1) s += __shfl_xor(s, o);
        const float inv = 1.f/s;
        #pragma unroll
        for (int j = 0; j < 8; ++j) alpha[i][l + 64*j] = e8[j]*inv;
    }
    __syncthreads();
    // phase B: aggregate + gelu -> xh2 (LDS only)
    const int h = l;
    float a0=0.f,a1=0.f,a2=0.f,a3=0.f;
    const float* Hb = Hbuf + (size_t)b*NN*HH + h;
    const float4* A0 = (const float4*)alpha[w];
    const float4* A1 = (const float4*)alpha[w+4];
    const float4* A2 = (const float4*)alpha[w+8];
    const float4* A3 = (const float4*)alpha[w+12];
    for (int g = 0; g < NN/4; ++g){
        float4 p0 = A0[g], p1 = A1[g], p2 = A2[g], p3 = A3[g];
        float h0 = Hb[(size_t)(4*g+0)*HH], h1 = Hb[(size_t)(4*g+1)*HH];
        float h2 = Hb[(size_t)(4*g+2)*HH], h3 = Hb[(size_t)(4*g+3)*HH];
        a0 += p0.x*h0 + p0.y*h1 + p0.z*h2 + p0.w*h3;
        a1 += p1.x*h0 + p1.y*h1 + p1.z*h2 + p1.w*h3;
        a2 += p2.x*h0 + p2.y*h1 + p2.z*h2 + p2.w*h3;
        a3 += p3.x*h0 + p3.y*h1 + p3.z*h2 + p3.w*h3;
    }
    const float bv = bias1[h];
    xh2[w   ][h] = gelu_exact(a0+bv);
    xh2[w+4 ][h] = gelu_exact(a1+bv);
    xh2[w+8 ][h] = gelu_exact(a2+bv);
    xh2[w+12][h] = gelu_exact(a3+bv);
    __syncthreads();
    // fused GAT2 pre
    for (int q = 0; q < 4; ++q){
        const int i = w + 4*q;
        float acc = 0.f;
        const float4* xr = (const float4*)&xh2[i][0];
        #pragma unroll
        for (int k4 = 0; k4 < 16; ++k4){
            float4 xv = xr[k4];
            acc += xv.x*sw2[(4*k4+0)*HH+h] + xv.y*sw2[(4*k4+1)*HH+h]
                 + xv.z*sw2[(4*k4+2)*HH+h] + xv.w*sw2[(4*k4+3)*HH+h];
        }
        const int m = b*NN + m0 + i;
        H2[(size_t)m*HH + h] = acc;
        float v1 = acc*sal[h], v2 = acc*sar[h];
        #pragma unroll
        for (int o = 32; o; o >>= 1){ v1 += __shfl_xor(v1,o); v2 += __shfl_xor(v2,o); }
        if (h == 0){ el2[m] = v1; er2[m] = v2; }
    }
}

// =============== K3: attn layer2 -> g2 ===============
__global__ __launch_bounds__(256,2) void attn2_kernel(
    const float* __restrict__ Hbuf, const float* __restrict__ el_in, const float* __restrict__ er_in,
    const int* __restrict__ ei, int E,
    const float* __restrict__ bias2, float* __restrict__ g2)
{
    __shared__ unsigned smask[16][16];
    __shared__ float er_s[NN];
    __shared__ float alpha[16][NN];
    const int t = threadIdx.x;
    const int b = blockIdx.x >> 5;
    const int m0 = (blockIdx.x & 31) * 16;
    const int l = t & 63, w = t >> 6;

    ((unsigned*)smask)[t] = 0;
    er_s[t] = er_in[b*NN + t];
    er_s[t+256] = er_in[b*NN + t + 256];
    __syncthreads();
    for (int e = t; e < E; e += 256){
        int s = ei[e];
        unsigned rl = (unsigned)(s - m0);
        if (rl < 16u){
            int d = ei[E + e];
            atomicOr(&smask[rl][d>>5], 1u << (d & 31));
        }
    }
    __syncthreads();
    for (int q = 0; q < 4; ++q){
        const int i = w*4 + q;
        const float elv = el_in[b*NN + m0 + i];
        float e8[8]; unsigned mk = 0; float mx = -1e30f;
        #pragma unroll
        for (int j = 0; j < 8; ++j){
            int n = l + 64*j;
            float ev = elv + er_s[n];
            ev = ev >= 0.f ? ev : 0.2f*ev;
            unsigned mb = (smask[i][(l>>5) + 2*j] >> (l & 31)) & 1u;
            e8[j] = ev;
            if (mb){ mk |= (1u<<j); mx = fmaxf(mx, ev); }
        }
        #pragma unroll
        for (int o = 32; o; o >>= 1) mx = fmaxf(mx, __shfl_xor(mx, o));
        float s = 0.f;
        #pragma unroll
        for (int j = 0; j < 8; ++j){
            float p = ((mk>>j) & 1u) ? __expf(e8[j]-mx) : 0.f;
            e8[j] = p; s += p;
        }
        #pragma unroll
        for (int o = 32; o; o >>= 1) s += __shfl_xor(s, o);
        const float inv = 1.f/s;
        #pragma unroll
        for (int j = 0; j < 8; ++j) alpha[i][l + 64*j] = e8[j]*inv;
    }
    __syncthreads();
    const int h = l;
    float a0=0.f,a1=0.f,a2=0.f,a3=0.f;
    const float* Hb = Hbuf + (size_t)b*NN*HH + h;
    const float4* A0 = (const float4*)alpha[w];
    const float4* A1 = (const float4*)alpha[w+4];
    const float4* A2 = (const float4*)alpha[w+8];
    const float4* A3 = (const float4*)alpha[w+12];
    for (int g = 0; g < NN/4; ++g){
        float4 p0 = A0[g], p1 = A1[g], p2 = A2[g], p3 = A3[g];
        float h0 = Hb[(size_t)(4*g+0)*HH], h1 = Hb[(size_t)(4*g+1)*HH];
        float h2 = Hb[(size_t)(4*g+2)*HH], h3 = Hb[(size_t)(4*g+3)*HH];
        a0 += p0.x*h0 + p0.y*h1 + p0.z*h2 + p0.w*h3;
        a1 += p1.x*h0 + p1.y*h1 + p1.z*h2 + p1.w*h3;
        a2 += p2.x*h0 + p2.y*h1 + p2.z*h2 + p2.w*h3;
        a3 += p3.x*h0 + p3.y*h1 + p3.z*h2 + p3.w*h3;
    }
    const float bv = bias2[h];
    const size_t base = (size_t)(b*NN + m0)*HH + h;
    g2[base + (size_t)(w   )*HH] = gelu_exact(a0+bv);
    g2[base + (size_t)(w+4 )*HH] = gelu_exact(a1+bv);
    g2[base + (size_t)(w+8 )*HH] = gelu_exact(a2+bv);
    g2[base + (size_t)(w+12)*HH] = gelu_exact(a3+bv);
}

// =============== K4: MFMA LSTM (prebuilt weights) + LN + decode ===============
#define LHS 72   // h row stride (bf16), 64 + 8 pad
#define LXS 40   // x row stride (bf16), 32 + 8 pad
__global__ __launch_bounds__(256,2) void lstm_final_kernel(
    const float* __restrict__ x,
    const float* __restrict__ wcombG, const float* __restrict__ bcombG,
    const unsigned short* __restrict__ whhfrag,
    const float* __restrict__ g2,
    const float* __restrict__ g_l, const float* __restrict__ b_l,
    const float* __restrict__ g_g, const float* __restrict__ b_g,
    const float* __restrict__ W_d, const float* __restrict__ b_d,
    float* __restrict__ out)
{
    __shared__ __align__(16) unsigned short hbi[2][16*LHS];
    __shared__ __align__(16) unsigned short hlo[2][16*LHS];
    __shared__ __align__(16) unsigned short xls[TT*16*LXS];
    __shared__ float hfin[16*HH];

    const int t = threadIdx.x;
    const int m0 = blockIdx.x * 16;
    const int lane = t & 63;
    const int w = t >> 6;
    const int quad = lane >> 4;
    const int c16 = lane & 15;

    // zero h buf0 + x pads
    {
        unsigned* h0 = (unsigned*)hbi[0];
        unsigned* l0 = (unsigned*)hlo[0];
        for (int i = t; i < 16*LHS/2; i += 256){ h0[i] = 0u; l0[i] = 0u; }
        unsigned* xw = (unsigned*)xls;
        for (int i = t; i < TT*16*LXS/2; i += 256) xw[i] = 0u;
    }
    // B-fragments from prebuilt global (coalesced 16B/lane)
    short8 bw[4][2]; short8 bx[4]; float bc[4];
    #pragma unroll
    for (int tt = 0; tt < 4; ++tt){
        const int ng = (w + 4*tt)*16 + c16;
        bc[tt] = bcombG[ng];
        #pragma unroll
        for (int ks = 0; ks < 2; ++ks)
            bw[tt][ks] = *(const short8*)&whhfrag[(((w*4+tt)*2)+ks)*512 + lane*8];
        short8 vx = {0,0,0,0,0,0,0,0};
        if (quad == 0){
            #pragma unroll
            for (int j = 0; j < 8; ++j) vx[j] = (short)f2bu(wcombG[j*256 + ng]);
        }
        bx[tt] = vx;
    }
    __syncthreads();
    // fill x (bf16) into padded LDS
    for (int i = t; i < 16*TT*NXF; i += 256){
        int r = i / (TT*NXF);
        int rem = i - r*(TT*NXF);
        int st = rem >> 3, f = rem & 7;
        xls[st*(16*LXS) + r*LXS + f] = f2bu(x[(size_t)(m0+r)*(TT*NXF) + rem]);
    }
    __syncthreads();

    float cst[4] = {0,0,0,0};
    float hf[4]  = {0,0,0,0};

    for (int st = 0; st < TT; ++st){
        const int p = st & 1;
        const unsigned short* hb = hbi[p];
        const unsigned short* hl_ = hlo[p];
        short8 ahi0 = *(const short8*)&hb[c16*LHS + quad*8];
        short8 ahi1 = *(const short8*)&hb[c16*LHS + 32 + quad*8];
        short8 alo0 = *(const short8*)&hl_[c16*LHS + quad*8];
        short8 alo1 = *(const short8*)&hl_[c16*LHS + 32 + quad*8];
        short8 ax   = *(const short8*)&xls[st*(16*LXS) + c16*LXS + quad*8];
        f32x4 acc[4];
        #pragma unroll
        for (int tt = 0; tt < 4; ++tt){
            f32x4 a = {bc[tt], bc[tt], bc[tt], bc[tt]};
            a = __builtin_amdgcn_mfma_f32_16x16x32_bf16(ax,   bx[tt],    a, 0,0,0);
            a = __builtin_amdgcn_mfma_f32_16x16x32_bf16(ahi0, bw[tt][0], a, 0,0,0);
            a = __builtin_amdgcn_mfma_f32_16x16x32_bf16(ahi1, bw[tt][1], a, 0,0,0);
            a = __builtin_amdgcn_mfma_f32_16x16x32_bf16(alo0, bw[tt][0], a, 0,0,0);
            a = __builtin_amdgcn_mfma_f32_16x16x32_bf16(alo1, bw[tt][1], a, 0,0,0);
            acc[tt] = a;
        }
        unsigned short* ho = hbi[p^1];
        unsigned short* lo_o = hlo[p^1];
        #pragma unroll
        for (int reg = 0; reg < 4; ++reg){
            float gi = acc[0][reg], gf = acc[1][reg], gg = acc[2][reg], go = acc[3][reg];
            float cn = sigm(gf)*cst[reg] + sigm(gi)*tanh_fast(gg);
            cst[reg] = cn;
            float hn = sigm(go)*tanh_fast(cn);
            hf[reg] = hn;
            unsigned short hu = f2bu(hn);
            float lov = hn - bu2f(hu);
            int addr = (quad*4+reg)*LHS + w*16 + c16;
            ho[addr] = hu;
            lo_o[addr] = f2bu(lov);
        }
        __syncthreads();
    }

    // epilogue: LN(g2)+LN(h) -> decode
    #pragma unroll
    for (int reg = 0; reg < 4; ++reg)
        hfin[(quad*4+reg)*HH + w*16 + c16] = hf[reg];
    __syncthreads();
    float* sdec = (float*)xls;
    const int h = lane;
    for (int q = 0; q < 4; ++q){
        const int ml = w*4 + q;
        float lv = hfin[ml*HH + h];
        float gv = g2[(size_t)(m0+ml)*HH + h];

        float s1 = gv;
        #pragma unroll
        for (int o = 32; o; o >>= 1) s1 += __shfl_xor(s1, o);
        float dg = gv - s1*(1.f/64.f);
        float v1 = dg*dg;
        #pragma unroll
        for (int o = 32; o; o >>= 1) v1 += __shfl_xor(v1, o);
        float lng = dg*rsqrtf(v1*(1.f/64.f) + 1e-5f)*g_g[h] + b_g[h];

        float s2 = lv;
        #pragma unroll
        for (int o = 32; o; o >>= 1) s2 += __shfl_xor(s2, o);
        float dl = lv - s2*(1.f/64.f);
        float v2 = dl*dl;
        #pragma unroll
        for (int o = 32; o; o >>= 1) v2 += __shfl_xor(v2, o);
        float lnl = dl*rsqrtf(v2*(1.f/64.f) + 1e-5f)*g_l[h] + b_l[h];

        sdec[ml*HH + h] = lng + lnl;
    }
    __syncthreads();
    if (t < 16*PRED){
        int rr = t / PRED, pp = t - rr*PRED;
        float acc = b_d[pp];
        #pragma unroll
        for (int k = 0; k < HH; ++k) acc += sdec[rr*HH + k]*W_d[k*PRED + pp];
        out[(size_t)(m0+rr)*PRED + pp] = acc;
    }
}

extern "C" void kernel_launch(void* const* d_in, const int* in_sizes, int n_in,
                              void* d_out, int out_size, void* d_ws, size_t ws_size,
                              hipStream_t stream){
    const float* x    = (const float*)d_in[0];
    const int*   ei   = (const int*)  d_in[1];
    const float* Wfc  = (const float*)d_in[2];
    const float* bfc  = (const float*)d_in[3];
    const float* W1   = (const float*)d_in[4];
    const float* al1  = (const float*)d_in[5];
    const float* ar1  = (const float*)d_in[6];
    const float* bias1= (const float*)d_in[7];
    const float* W2   = (const float*)d_in[8];
    const float* al2  = (const float*)d_in[9];
    const float* ar2  = (const float*)d_in[10];
    const float* bias2= (const float*)d_in[11];
    const float* Wih  = (const float*)d_in[12];
    const float* Whh  = (const float*)d_in[13];
    const float* bih  = (const float*)d_in[14];
    const float* bhh  = (const float*)d_in[15];
    const float* g_l  = (const float*)d_in[16];
    const float* b_l  = (const float*)d_in[17];
    const float* g_g  = (const float*)d_in[18];
    const float* b_g  = (const float*)d_in[19];
    const float* W_d  = (const float*)d_in[20];
    const float* b_d  = (const float*)d_in[21];

    float* ws = (float*)d_ws;
    const int E = in_sizes[1] / 2;

    gat1pre_kernel<<<512 + 8, 256, 0, stream>>>(x, Wfc, bfc, W1, al1, ar1,
                                                Wih, Whh, bih, bhh,
                                                ws+WS_HBUF, ws+WS_EL, ws+WS_ER,
                                                ws+WS_WCOMB, ws+WS_BCOMB,
                                                (unsigned short*)(ws+WS_WHHFRAG));
    attn_fuse_kernel<<<BB*(NN/16), 256, 0, stream>>>(ws+WS_HBUF, ws+WS_EL, ws+WS_ER,
                                                     ei, E, bias1, W2, al2, ar2,
                                                     ws+WS_H2, ws+WS_EL2, ws+WS_ER2);
    attn2_kernel<<<BB*(NN/16), 256, 0, stream>>>(ws+WS_H2, ws+WS_EL2, ws+WS_ER2,
                                                 ei, E, bias2, ws+WS_G2);
    lstm_final_kernel<<<MM/16, 256, 0, stream>>>(x, ws+WS_WCOMB, ws+WS_BCOMB,
                                                 (const unsigned short*)(ws+WS_WHHFRAG),
                                                 ws+WS_G2, g_l, b_l, g_g, b_g, W_d, b_d,
                                                 (float*)d_out);
}

// Round 6
// 180.506 us; speedup vs baseline: 1.2129x; 1.0834x over previous
//
#include <hip/hip_runtime.h>
#include <hip/hip_bf16.h>
#include <math.h>

#define BB 4
#define NN 512
#define TT 24
#define NXF 8
#define HH 64
#define PRED 12
#define MM (BB*NN)   // 2048

typedef __attribute__((ext_vector_type(8))) short short8;
typedef __attribute__((ext_vector_type(4))) float f32x4;

// ---- workspace layout (float offsets) ----
#define WS_HBUF    0         // 131072  H1
#define WS_H2      131072    // 131072  H2
#define WS_G2      262144    // 131072  g2
#define WS_EL      393216    // 2048
#define WS_ER      395264    // 2048
#define WS_EL2     397312    // 2048
#define WS_ER2     399360    // 2048
#define WS_WCOMB   401408    // 2048 f32
#define WS_BCOMB   403456    // 256  f32
#define WS_WHHFRAG 403712    // 16384 bf16 (= 8192 f32 slots)

__device__ inline float sigm(float x){ return 1.f/(1.f+__expf(-x)); }
__device__ inline float tanh_fast(float x){ float e=__expf(2.f*x); return 1.f - 2.f/(e+1.f); }
__device__ inline float gelu_exact(float x){ return 0.5f*x*(1.f+erff(x*0.70710678118654752440f)); }
__device__ inline unsigned short f2bu(float f){           // RNE f32 -> bf16 bits
    unsigned b=__float_as_uint(f);
    return (unsigned short)((b + 0x7FFFu + ((b>>16)&1u))>>16);
}
__device__ inline float bu2f(unsigned short u){ return __uint_as_float(((unsigned)u)<<16); }

// split 8 f32 into hi/lo bf16 frags
__device__ inline void split8(const float* f, short8& hi, short8& lo){
    #pragma unroll
    for (int j = 0; j < 8; ++j){
        unsigned short h = f2bu(f[j]);
        hi[j] = (short)h;
        lo[j] = (short)f2bu(f[j] - bu2f(h));
    }
}

// =============== K1: H1 = (x_last @ Wfc + bfc) @ W1 ; el1, er1 (+ LSTM precomp blocks) ===============
__global__ __launch_bounds__(256,2) void gat1pre_kernel(
    const float* __restrict__ x, const float* __restrict__ Wfc, const float* __restrict__ bfc,
    const float* __restrict__ W1, const float* __restrict__ al1, const float* __restrict__ ar1,
    const float* __restrict__ Wih, const float* __restrict__ Whh,
    const float* __restrict__ bih, const float* __restrict__ bhh,
    float* __restrict__ Hbuf, float* __restrict__ el, float* __restrict__ er,
    float* __restrict__ wcombG, float* __restrict__ bcombG,
    unsigned short* __restrict__ whhfrag)
{
    __shared__ float sw1[HH*HH];
    __shared__ float swfc[NXF*HH];
    __shared__ float sb[HH], sal[HH], sar[HH];
    __shared__ float sxh[4][68];
    __shared__ float sx[4][NXF];
    const int t = threadIdx.x;

    if (blockIdx.x >= 512){
        const int f = blockIdx.x - 512;   // 0..7
        const int ng = t;
        float accf = 0.f, accb = 0.f;
        const float* wr = Wih + ng*64;
        #pragma unroll
        for (int k = 0; k < 64; ++k){
            float wv = wr[k];
            accf += Wfc[f*64 + k] * wv;
            accb += bfc[k] * wv;
        }
        wcombG[f*256 + ng] = accf;
        if (f == 0) bcombG[ng] = accb + bih[ng] + bhh[ng];
        #pragma unroll
        for (int u = 0; u < 8; ++u){
            int o = f*2048 + u*256 + t;
            int F  = o >> 9;
            int ln = (o >> 3) & 63;
            int j  = o & 7;
            int w_ = F >> 3, tt = (F >> 1) & 3, ks = F & 1;
            int q = ln >> 4, c = ln & 15;
            int ngx = (w_ + 4*tt)*16 + c;
            whhfrag[o] = f2bu(Whh[ngx*64 + ks*32 + q*8 + j]);
        }
        return;
    }

    const int r = t >> 6, h = t & 63;
    #pragma unroll
    for (int i = 0; i < 16; ++i) sw1[t + 256*i] = W1[t + 256*i];
    swfc[t] = Wfc[t];
    swfc[t+256] = Wfc[t+256];
    if (t < 64) sb[t] = bfc[t];
    else if (t < 128) sal[t-64] = al1[t-64];
    else if (t < 192) sar[t-128] = ar1[t-128];
    if (t < 32){
        int rr = t >> 3, f = t & 7;
        sx[rr][f] = x[(size_t)(blockIdx.x*4 + rr)*(TT*NXF) + (TT-1)*NXF + f];
    }
    __syncthreads();
    float xh = sb[h];
    #pragma unroll
    for (int f = 0; f < NXF; ++f) xh += sx[r][f]*swfc[f*HH + h];
    sxh[r][h] = xh;
    __syncthreads();
    float acc = 0.f;
    const float4* xr = (const float4*)&sxh[r][0];
    #pragma unroll
    for (int k4 = 0; k4 < 16; ++k4){
        float4 xv = xr[k4];
        acc += xv.x*sw1[(4*k4+0)*HH+h] + xv.y*sw1[(4*k4+1)*HH+h]
             + xv.z*sw1[(4*k4+2)*HH+h] + xv.w*sw1[(4*k4+3)*HH+h];
    }
    const int m = blockIdx.x*4 + r;
    Hbuf[(size_t)m*HH + h] = acc;
    float v1 = acc*sal[h], v2 = acc*sar[h];
    #pragma unroll
    for (int o = 32; o; o >>= 1){ v1 += __shfl_xor(v1,o); v2 += __shfl_xor(v2,o); }
    if (h == 0){ el[m] = v1; er[m] = v2; }
}

// =============== K2: attn layer1 (MFMA phase-B) + fused GAT2-pre ===============
__global__ __launch_bounds__(256,2) void attn_fuse_kernel(
    const float* __restrict__ Hbuf, const float* __restrict__ el_in, const float* __restrict__ er_in,
    const int* __restrict__ ei, int E,
    const float* __restrict__ bias1,
    const float* __restrict__ W2, const float* __restrict__ al2, const float* __restrict__ ar2,
    float* __restrict__ H2, float* __restrict__ el2, float* __restrict__ er2)
{
    __shared__ unsigned smask[16][16];
    __shared__ float er_s[NN];
    __shared__ float alpha[16][516];
    __shared__ __align__(16) float uSpace[64*70];   // HT f32 tile; later sw2 (16 KB)
    __shared__ float xh2[16][68];
    __shared__ float sal[HH], sar[HH];

    const int t = threadIdx.x;
    const int b = blockIdx.x >> 5;
    const int m0 = (blockIdx.x & 31) * 16;
    const int l = t & 63, w = t >> 6;
    const int quad = l >> 4, c16 = l & 15;
    float (*HT)[70] = (float(*)[70])uSpace;

    if (t < 64) sal[t] = al2[t]; else if (t < 128) sar[t-64] = ar2[t-64];
    ((unsigned*)smask)[t] = 0;
    er_s[t] = er_in[b*NN + t];
    er_s[t+256] = er_in[b*NN + t + 256];
    __syncthreads();
    for (int e = t; e < E; e += 256){
        int s = ei[e];
        unsigned rl = (unsigned)(s - m0);
        if (rl < 16u){
            int d = ei[E + e];
            atomicOr(&smask[rl][d>>5], 1u << (d & 31));
        }
    }
    // prefetch H tile 0 into regs (hide under phase A)
    const float* Hbase = Hbuf + (size_t)b*NN*HH;
    const int nn = t >> 2, cc = t & 3;
    float4 r0,r1,r2,r3;
    {
        const float4* src = (const float4*)(Hbase + (size_t)nn*HH + cc*16);
        r0 = src[0]; r1 = src[1]; r2 = src[2]; r3 = src[3];
    }
    __syncthreads();
    // phase A: masked softmax -> alpha (f32, padded rows)
    for (int q = 0; q < 4; ++q){
        const int i = w*4 + q;
        const float elv = el_in[b*NN + m0 + i];
        float e8[8]; unsigned mk = 0; float mx = -1e30f;
        #pragma unroll
        for (int j = 0; j < 8; ++j){
            int n = l + 64*j;
            float ev = elv + er_s[n];
            ev = ev >= 0.f ? ev : 0.2f*ev;
            unsigned mb = (smask[i][(l>>5) + 2*j] >> (l & 31)) & 1u;
            e8[j] = ev;
            if (mb){ mk |= (1u<<j); mx = fmaxf(mx, ev); }
        }
        #pragma unroll
        for (int o = 32; o; o >>= 1) mx = fmaxf(mx, __shfl_xor(mx, o));
        float s = 0.f;
        #pragma unroll
        for (int j = 0; j < 8; ++j){
            float p = ((mk>>j) & 1u) ? __expf(e8[j]-mx) : 0.f;
            e8[j] = p; s += p;
        }
        #pragma unroll
        for (int o = 32; o; o >>= 1) s += __shfl_xor(s, o);
        const float inv = 1.f/s;
        #pragma unroll
        for (int j = 0; j < 8; ++j) alpha[i][l + 64*j] = e8[j]*inv;
    }
    __syncthreads();   // alpha ready, HT free

    // phase B: C(16x64) = alpha(16x512) @ H(512x64) via MFMA, hi/lo split
    f32x4 acc = {0.f,0.f,0.f,0.f};
    for (int tile = 0; tile < 8; ++tile){
        // write staged regs -> HT transposed
        {
            float v[16] = {r0.x,r0.y,r0.z,r0.w, r1.x,r1.y,r1.z,r1.w,
                           r2.x,r2.y,r2.z,r2.w, r3.x,r3.y,r3.z,r3.w};
            #pragma unroll
            for (int jj = 0; jj < 16; ++jj) HT[cc*16 + jj][nn] = v[jj];
        }
        if (tile < 7){
            const float4* src = (const float4*)(Hbase + (size_t)((tile+1)*64 + nn)*HH + cc*16);
            r0 = src[0]; r1 = src[1]; r2 = src[2]; r3 = src[3];
        }
        __syncthreads();
        #pragma unroll
        for (int ks = 0; ks < 2; ++ks){
            const int k0 = tile*64 + ks*32;
            const float* ap = &alpha[c16][k0 + quad*8];
            float4 a0 = *(const float4*)ap;
            float4 a1 = *(const float4*)(ap + 4);
            const float* bp = &HT[w*16 + c16][ks*32 + quad*8];
            float2 b0 = *(const float2*)bp,     b1 = *(const float2*)(bp+2);
            float2 b2 = *(const float2*)(bp+4), b3 = *(const float2*)(bp+6);
            float af[8] = {a0.x,a0.y,a0.z,a0.w,a1.x,a1.y,a1.z,a1.w};
            float bf[8] = {b0.x,b0.y,b1.x,b1.y,b2.x,b2.y,b3.x,b3.y};
            short8 ahi, alo, bhi, blo;
            split8(af, ahi, alo);
            split8(bf, bhi, blo);
            acc = __builtin_amdgcn_mfma_f32_16x16x32_bf16(ahi, bhi, acc, 0,0,0);
            acc = __builtin_amdgcn_mfma_f32_16x16x32_bf16(alo, bhi, acc, 0,0,0);
            acc = __builtin_amdgcn_mfma_f32_16x16x32_bf16(ahi, blo, acc, 0,0,0);
        }
        __syncthreads();
    }
    // epilogue of phase B: bias + gelu -> xh2 (C-layout: row=quad*4+reg, col h=w*16+c16)
    {
        const int h = w*16 + c16;
        const float bv = bias1[h];
        #pragma unroll
        for (int reg = 0; reg < 4; ++reg)
            xh2[quad*4 + reg][h] = gelu_exact(acc[reg] + bv);
    }
    __syncthreads();
    // load sw2 into uSpace (HT dead)
    float* sw2 = uSpace;
    #pragma unroll
    for (int i = 0; i < 16; ++i) sw2[t + 256*i] = W2[t + 256*i];
    __syncthreads();
    // fused GAT2 pre: H2 = g1 @ W2 ; el2, er2
    {
        const int h = l;
        for (int q = 0; q < 4; ++q){
            const int i = w + 4*q;
            float acc2 = 0.f;
            const float4* xr = (const float4*)&xh2[i][0];
            #pragma unroll
            for (int k4 = 0; k4 < 16; ++k4){
                float4 xv = xr[k4];
                acc2 += xv.x*sw2[(4*k4+0)*HH+h] + xv.y*sw2[(4*k4+1)*HH+h]
                      + xv.z*sw2[(4*k4+2)*HH+h] + xv.w*sw2[(4*k4+3)*HH+h];
            }
            const int m = b*NN + m0 + i;
            H2[(size_t)m*HH + h] = acc2;
            float v1 = acc2*sal[h], v2 = acc2*sar[h];
            #pragma unroll
            for (int o = 32; o; o >>= 1){ v1 += __shfl_xor(v1,o); v2 += __shfl_xor(v2,o); }
            if (h == 0){ el2[m] = v1; er2[m] = v2; }
        }
    }
}

// =============== K3: attn layer2 (MFMA phase-B) -> g2 ===============
__global__ __launch_bounds__(256,2) void attn2_kernel(
    const float* __restrict__ Hbuf, const float* __restrict__ el_in, const float* __restrict__ er_in,
    const int* __restrict__ ei, int E,
    const float* __restrict__ bias2, float* __restrict__ g2)
{
    __shared__ unsigned smask[16][16];
    __shared__ float er_s[NN];
    __shared__ float alpha[16][516];
    __shared__ __align__(16) float uSpace[64*70];
    const int t = threadIdx.x;
    const int b = blockIdx.x >> 5;
    const int m0 = (blockIdx.x & 31) * 16;
    const int l = t & 63, w = t >> 6;
    const int quad = l >> 4, c16 = l & 15;
    float (*HT)[70] = (float(*)[70])uSpace;

    ((unsigned*)smask)[t] = 0;
    er_s[t] = er_in[b*NN + t];
    er_s[t+256] = er_in[b*NN + t + 256];
    __syncthreads();
    for (int e = t; e < E; e += 256){
        int s = ei[e];
        unsigned rl = (unsigned)(s - m0);
        if (rl < 16u){
            int d = ei[E + e];
            atomicOr(&smask[rl][d>>5], 1u << (d & 31));
        }
    }
    const float* Hbase = Hbuf + (size_t)b*NN*HH;
    const int nn = t >> 2, cc = t & 3;
    float4 r0,r1,r2,r3;
    {
        const float4* src = (const float4*)(Hbase + (size_t)nn*HH + cc*16);
        r0 = src[0]; r1 = src[1]; r2 = src[2]; r3 = src[3];
    }
    __syncthreads();
    for (int q = 0; q < 4; ++q){
        const int i = w*4 + q;
        const float elv = el_in[b*NN + m0 + i];
        float e8[8]; unsigned mk = 0; float mx = -1e30f;
        #pragma unroll
        for (int j = 0; j < 8; ++j){
            int n = l + 64*j;
            float ev = elv + er_s[n];
            ev = ev >= 0.f ? ev : 0.2f*ev;
            unsigned mb = (smask[i][(l>>5) + 2*j] >> (l & 31)) & 1u;
            e8[j] = ev;
            if (mb){ mk |= (1u<<j); mx = fmaxf(mx, ev); }
        }
        #pragma unroll
        for (int o = 32; o; o >>= 1) mx = fmaxf(mx, __shfl_xor(mx, o));
        float s = 0.f;
        #pragma unroll
        for (int j = 0; j < 8; ++j){
            float p = ((mk>>j) & 1u) ? __expf(e8[j]-mx) : 0.f;
            e8[j] = p; s += p;
        }
        #pragma unroll
        for (int o = 32; o; o >>= 1) s += __shfl_xor(s, o);
        const float inv = 1.f/s;
        #pragma unroll
        for (int j = 0; j < 8; ++j) alpha[i][l + 64*j] = e8[j]*inv;
    }
    __syncthreads();

    f32x4 acc = {0.f,0.f,0.f,0.f};
    for (int tile = 0; tile < 8; ++tile){
        {
            float v[16] = {r0.x,r0.y,r0.z,r0.w, r1.x,r1.y,r1.z,r1.w,
                           r2.x,r2.y,r2.z,r2.w, r3.x,r3.y,r3.z,r3.w};
            #pragma unroll
            for (int jj = 0; jj < 16; ++jj) HT[cc*16 + jj][nn] = v[jj];
        }
        if (tile < 7){
            const float4* src = (const float4*)(Hbase + (size_t)((tile+1)*64 + nn)*HH + cc*16);
            r0 = src[0]; r1 = src[1]; r2 = src[2]; r3 = src[3];
        }
        __syncthreads();
        #pragma unroll
        for (int ks = 0; ks < 2; ++ks){
            const int k0 = tile*64 + ks*32;
            const float* ap = &alpha[c16][k0 + quad*8];
            float4 a0 = *(const float4*)ap;
            float4 a1 = *(const float4*)(ap + 4);
            const float* bp = &HT[w*16 + c16][ks*32 + quad*8];
            float2 b0 = *(const float2*)bp,     b1 = *(const float2*)(bp+2);
            float2 b2 = *(const float2*)(bp+4), b3 = *(const float2*)(bp+6);
            float af[8] = {a0.x,a0.y,a0.z,a0.w,a1.x,a1.y,a1.z,a1.w};
            float bf[8] = {b0.x,b0.y,b1.x,b1.y,b2.x,b2.y,b3.x,b3.y};
            short8 ahi, alo, bhi, blo;
            split8(af, ahi, alo);
            split8(bf, bhi, blo);
            acc = __builtin_amdgcn_mfma_f32_16x16x32_bf16(ahi, bhi, acc, 0,0,0);
            acc = __builtin_amdgcn_mfma_f32_16x16x32_bf16(alo, bhi, acc, 0,0,0);
            acc = __builtin_amdgcn_mfma_f32_16x16x32_bf16(ahi, blo, acc, 0,0,0);
        }
        __syncthreads();
    }
    {
        const int h = w*16 + c16;
        const float bv = bias2[h];
        #pragma unroll
        for (int reg = 0; reg < 4; ++reg)
            g2[(size_t)(b*NN + m0 + quad*4 + reg)*HH + h] = gelu_exact(acc[reg] + bv);
    }
}

// =============== K4: MFMA LSTM (prebuilt weights) + LN + decode ===============
#define LHS 72
#define LXS 40
__global__ __launch_bounds__(256,2) void lstm_final_kernel(
    const float* __restrict__ x,
    const float* __restrict__ wcombG, const float* __restrict__ bcombG,
    const unsigned short* __restrict__ whhfrag,
    const float* __restrict__ g2,
    const float* __restrict__ g_l, const float* __restrict__ b_l,
    const float* __restrict__ g_g, const float* __restrict__ b_g,
    const float* __restrict__ W_d, const float* __restrict__ b_d,
    float* __restrict__ out)
{
    __shared__ __align__(16) unsigned short hbi[2][16*LHS];
    __shared__ __align__(16) unsigned short hlo[2][16*LHS];
    __shared__ __align__(16) unsigned short xls[TT*16*LXS];
    __shared__ float hfin[16*HH];

    const int t = threadIdx.x;
    const int m0 = blockIdx.x * 16;
    const int lane = t & 63;
    const int w = t >> 6;
    const int quad = lane >> 4;
    const int c16 = lane & 15;

    {
        unsigned* h0 = (unsigned*)hbi[0];
        unsigned* l0 = (unsigned*)hlo[0];
        for (int i = t; i < 16*LHS/2; i += 256){ h0[i] = 0u; l0[i] = 0u; }
        unsigned* xw = (unsigned*)xls;
        for (int i = t; i < TT*16*LXS/2; i += 256) xw[i] = 0u;
    }
    short8 bw[4][2]; short8 bx[4]; float bc[4];
    #pragma unroll
    for (int tt = 0; tt < 4; ++tt){
        const int ng = (w + 4*tt)*16 + c16;
        bc[tt] = bcombG[ng];
        #pragma unroll
        for (int ks = 0; ks < 2; ++ks)
            bw[tt][ks] = *(const short8*)&whhfrag[(((w*4+tt)*2)+ks)*512 + lane*8];
        short8 vx = {0,0,0,0,0,0,0,0};
        if (quad == 0){
            #pragma unroll
            for (int j = 0; j < 8; ++j) vx[j] = (short)f2bu(wcombG[j*256 + ng]);
        }
        bx[tt] = vx;
    }
    __syncthreads();
    for (int i = t; i < 16*TT*NXF; i += 256){
        int r = i / (TT*NXF);
        int rem = i - r*(TT*NXF);
        int st = rem >> 3, f = rem & 7;
        xls[st*(16*LXS) + r*LXS + f] = f2bu(x[(size_t)(m0+r)*(TT*NXF) + rem]);
    }
    __syncthreads();

    float cst[4] = {0,0,0,0};
    float hf[4]  = {0,0,0,0};

    for (int st = 0; st < TT; ++st){
        const int p = st & 1;
        const unsigned short* hb = hbi[p];
        const unsigned short* hl_ = hlo[p];
        short8 ahi0 = *(const short8*)&hb[c16*LHS + quad*8];
        short8 ahi1 = *(const short8*)&hb[c16*LHS + 32 + quad*8];
        short8 alo0 = *(const short8*)&hl_[c16*LHS + quad*8];
        short8 alo1 = *(const short8*)&hl_[c16*LHS + 32 + quad*8];
        short8 ax   = *(const short8*)&xls[st*(16*LXS) + c16*LXS + quad*8];
        f32x4 acc[4];
        #pragma unroll
        for (int tt = 0; tt < 4; ++tt){
            f32x4 a = {bc[tt], bc[tt], bc[tt], bc[tt]};
            a = __builtin_amdgcn_mfma_f32_16x16x32_bf16(ax,   bx[tt],    a, 0,0,0);
            a = __builtin_amdgcn_mfma_f32_16x16x32_bf16(ahi0, bw[tt][0], a, 0,0,0);
            a = __builtin_amdgcn_mfma_f32_16x16x32_bf16(ahi1, bw[tt][1], a, 0,0,0);
            a = __builtin_amdgcn_mfma_f32_16x16x32_bf16(alo0, bw[tt][0], a, 0,0,0);
            a = __builtin_amdgcn_mfma_f32_16x16x32_bf16(alo1, bw[tt][1], a, 0,0,0);
            acc[tt] = a;
        }
        unsigned short* ho = hbi[p^1];
        unsigned short* lo_o = hlo[p^1];
        #pragma unroll
        for (int reg = 0; reg < 4; ++reg){
            float gi = acc[0][reg], gf = acc[1][reg], gg = acc[2][reg], go = acc[3][reg];
            float cn = sigm(gf)*cst[reg] + sigm(gi)*tanh_fast(gg);
            cst[reg] = cn;
            float hn = sigm(go)*tanh_fast(cn);
            hf[reg] = hn;
            unsigned short hu = f2bu(hn);
            float lov = hn - bu2f(hu);
            int addr = (quad*4+reg)*LHS + w*16 + c16;
            ho[addr] = hu;
            lo_o[addr] = f2bu(lov);
        }
        __syncthreads();
    }

    #pragma unroll
    for (int reg = 0; reg < 4; ++reg)
        hfin[(quad*4+reg)*HH + w*16 + c16] = hf[reg];
    __syncthreads();
    float* sdec = (float*)xls;
    const int h = lane;
    for (int q = 0; q < 4; ++q){
        const int ml = w*4 + q;
        float lv = hfin[ml*HH + h];
        float gv = g2[(size_t)(m0+ml)*HH + h];

        float s1 = gv;
        #pragma unroll
        for (int o = 32; o; o >>= 1) s1 += __shfl_xor(s1, o);
        float dg = gv - s1*(1.f/64.f);
        float v1 = dg*dg;
        #pragma unroll
        for (int o = 32; o; o >>= 1) v1 += __shfl_xor(v1, o);
        float lng = dg*rsqrtf(v1*(1.f/64.f) + 1e-5f)*g_g[h] + b_g[h];

        float s2 = lv;
        #pragma unroll
        for (int o = 32; o; o >>= 1) s2 += __shfl_xor(s2, o);
        float dl = lv - s2*(1.f/64.f);
        float v2 = dl*dl;
        #pragma unroll
        for (int o = 32; o; o >>= 1) v2 += __shfl_xor(v2, o);
        float lnl = dl*rsqrtf(v2*(1.f/64.f) + 1e-5f)*g_l[h] + b_l[h];

        sdec[ml*HH + h] = lng + lnl;
    }
    __syncthreads();
    if (t < 16*PRED){
        int rr = t / PRED, pp = t - rr*PRED;
        float acc = b_d[pp];
        #pragma unroll
        for (int k = 0; k < HH; ++k) acc += sdec[rr*HH + k]*W_d[k*PRED + pp];
        out[(size_t)(m0+rr)*PRED + pp] = acc;
    }
}

extern "C" void kernel_launch(void* const* d_in, const int* in_sizes, int n_in,
                              void* d_out, int out_size, void* d_ws, size_t ws_size,
                              hipStream_t stream){
    const float* x    = (const float*)d_in[0];
    const int*   ei   = (const int*)  d_in[1];
    const float* Wfc  = (const float*)d_in[2];
    const float* bfc  = (const float*)d_in[3];
    const float* W1   = (const float*)d_in[4];
    const float* al1  = (const float*)d_in[5];
    const float* ar1  = (const float*)d_in[6];
    const float* bias1= (const float*)d_in[7];
    const float* W2   = (const float*)d_in[8];
    const float* al2  = (const float*)d_in[9];
    const float* ar2  = (const float*)d_in[10];
    const float* bias2= (const float*)d_in[11];
    const float* Wih  = (const float*)d_in[12];
    const float* Whh  = (const float*)d_in[13];
    const float* bih  = (const float*)d_in[14];
    const float* bhh  = (const float*)d_in[15];
    const float* g_l  = (const float*)d_in[16];
    const float* b_l  = (const float*)d_in[17];
    const float* g_g  = (const float*)d_in[18];
    const float* b_g  = (const float*)d_in[19];
    const float* W_d  = (const float*)d_in[20];
    const float* b_d  = (const float*)d_in[21];

    float* ws = (float*)d_ws;
    const int E = in_sizes[1] / 2;

    gat1pre_kernel<<<512 + 8, 256, 0, stream>>>(x, Wfc, bfc, W1, al1, ar1,
                                                Wih, Whh, bih, bhh,
                                                ws+WS_HBUF, ws+WS_EL, ws+WS_ER,
                                                ws+WS_WCOMB, ws+WS_BCOMB,
                                                (unsigned short*)(ws+WS_WHHFRAG));
    attn_fuse_kernel<<<BB*(NN/16), 256, 0, stream>>>(ws+WS_HBUF, ws+WS_EL, ws+WS_ER,
                                                     ei, E, bias1, W2, al2, ar2,
                                                     ws+WS_H2, ws+WS_EL2, ws+WS_ER2);
    attn2_kernel<<<BB*(NN/16), 256, 0, stream>>>(ws+WS_H2, ws+WS_EL2, ws+WS_ER2,
                                                 ei, E, bias2, ws+WS_G2);
    lstm_final_kernel<<<MM/16, 256, 0, stream>>>(x, ws+WS_WCOMB, ws+WS_BCOMB,
                                                 (const unsigned short*)(ws+WS_WHHFRAG),
                                                 ws+WS_G2, g_l, b_l, g_g, b_g, W_d, b_d,
                                                 (float*)d_out);
}

// Round 7
// 150.725 us; speedup vs baseline: 1.4525x; 1.1976x over previous
//
#include <hip/hip_runtime.h>
#include <hip/hip_bf16.h>
#include <math.h>

#define BB 4
#define NN 512
#define TT 24
#define NXF 8
#define HH 64
#define PRED 12
#define MM (BB*NN)   // 2048

typedef __attribute__((ext_vector_type(8))) short short8;
typedef __attribute__((ext_vector_type(4))) float f32x4;
typedef unsigned short ushort;

// ---- workspace layout (float offsets) ----
#define WS_HBUF    0         // 131072  H1
#define WS_H2      131072    // 131072  H2
#define WS_HL      262144    // 131072  lstm final h
#define WS_EL      393216    // 2048
#define WS_ER      395264    // 2048
#define WS_EL2     397312    // 2048
#define WS_ER2     399360    // 2048
#define WS_WCOMB   401408    // 2048 f32
#define WS_BCOMB   403456    // 256  f32
#define WS_WHHFRAG 403712    // 16384 bf16 (= 8192 f32 slots)

__device__ inline float sigm(float x){ return 1.f/(1.f+__expf(-x)); }
__device__ inline float tanh_fast(float x){ float e=__expf(2.f*x); return 1.f - 2.f/(e+1.f); }
__device__ inline float gelu_exact(float x){ return 0.5f*x*(1.f+erff(x*0.70710678118654752440f)); }
__device__ inline ushort f2bu(float f){           // RNE f32 -> bf16 bits
    unsigned b=__float_as_uint(f);
    return (ushort)((b + 0x7FFFu + ((b>>16)&1u))>>16);
}
__device__ inline float bu2f(ushort u){ return __uint_as_float(((unsigned)u)<<16); }

__device__ inline void split8(const float* f, short8& hi, short8& lo){
    #pragma unroll
    for (int j = 0; j < 8; ++j){
        ushort h = f2bu(f[j]);
        hi[j] = (short)h;
        lo[j] = (short)f2bu(f[j] - bu2f(h));
    }
}

// =============== K1: H1 = (x_last @ Wfc + bfc) @ W1 ; el1, er1 (+ LSTM precomp blocks) ===============
__global__ __launch_bounds__(256,2) void gat1pre_kernel(
    const float* __restrict__ x, const float* __restrict__ Wfc, const float* __restrict__ bfc,
    const float* __restrict__ W1, const float* __restrict__ al1, const float* __restrict__ ar1,
    const float* __restrict__ Wih, const float* __restrict__ Whh,
    const float* __restrict__ bih, const float* __restrict__ bhh,
    float* __restrict__ Hbuf, float* __restrict__ el, float* __restrict__ er,
    float* __restrict__ wcombG, float* __restrict__ bcombG,
    ushort* __restrict__ whhfrag)
{
    __shared__ float sw1[HH*HH];
    __shared__ float swfc[NXF*HH];
    __shared__ float sb[HH], sal[HH], sar[HH];
    __shared__ float sxh[4][68];
    __shared__ float sx[4][NXF];
    const int t = threadIdx.x;

    if (blockIdx.x >= 512){
        const int f = blockIdx.x - 512;   // 0..7
        const int ng = t;
        float accf = 0.f, accb = 0.f;
        const float* wr = Wih + ng*64;
        #pragma unroll
        for (int k = 0; k < 64; ++k){
            float wv = wr[k];
            accf += Wfc[f*64 + k] * wv;
            accb += bfc[k] * wv;
        }
        wcombG[f*256 + ng] = accf;
        if (f == 0) bcombG[ng] = accb + bih[ng] + bhh[ng];
        #pragma unroll
        for (int u = 0; u < 8; ++u){
            int o = f*2048 + u*256 + t;
            int F  = o >> 9;
            int ln = (o >> 3) & 63;
            int j  = o & 7;
            int w_ = F >> 3, tt = (F >> 1) & 3, ks = F & 1;
            int q = ln >> 4, c = ln & 15;
            int ngx = (w_ + 4*tt)*16 + c;
            whhfrag[o] = f2bu(Whh[ngx*64 + ks*32 + q*8 + j]);
        }
        return;
    }

    const int r = t >> 6, h = t & 63;
    #pragma unroll
    for (int i = 0; i < 16; ++i) sw1[t + 256*i] = W1[t + 256*i];
    swfc[t] = Wfc[t];
    swfc[t+256] = Wfc[t+256];
    if (t < 64) sb[t] = bfc[t];
    else if (t < 128) sal[t-64] = al1[t-64];
    else if (t < 192) sar[t-128] = ar1[t-128];
    if (t < 32){
        int rr = t >> 3, f = t & 7;
        sx[rr][f] = x[(size_t)(blockIdx.x*4 + rr)*(TT*NXF) + (TT-1)*NXF + f];
    }
    __syncthreads();
    float xh = sb[h];
    #pragma unroll
    for (int f = 0; f < NXF; ++f) xh += sx[r][f]*swfc[f*HH + h];
    sxh[r][h] = xh;
    __syncthreads();
    float acc = 0.f;
    const float4* xr = (const float4*)&sxh[r][0];
    #pragma unroll
    for (int k4 = 0; k4 < 16; ++k4){
        float4 xv = xr[k4];
        acc += xv.x*sw1[(4*k4+0)*HH+h] + xv.y*sw1[(4*k4+1)*HH+h]
             + xv.z*sw1[(4*k4+2)*HH+h] + xv.w*sw1[(4*k4+3)*HH+h];
    }
    const int m = blockIdx.x*4 + r;
    Hbuf[(size_t)m*HH + h] = acc;
    float v1 = acc*sal[h], v2 = acc*sar[h];
    #pragma unroll
    for (int o = 32; o; o >>= 1){ v1 += __shfl_xor(v1,o); v2 += __shfl_xor(v2,o); }
    if (h == 0){ el[m] = v1; er[m] = v2; }
}

// =============== K2: blocks 0-127 = attn layer1 + GAT2-pre ; blocks 128-255 = LSTM -> hl ===============
#define LHS 72
#define LXS 40
__global__ __launch_bounds__(256,2) void mid_fused_kernel(
    const float* __restrict__ Hbuf, const float* __restrict__ el_in, const float* __restrict__ er_in,
    const int* __restrict__ ei, int E,
    const float* __restrict__ bias1,
    const float* __restrict__ W2, const float* __restrict__ al2, const float* __restrict__ ar2,
    float* __restrict__ H2, float* __restrict__ el2, float* __restrict__ er2,
    const float* __restrict__ x,
    const float* __restrict__ wcombG, const float* __restrict__ bcombG,
    const ushort* __restrict__ whhfrag,
    float* __restrict__ hl)
{
    __shared__ __align__(16) char smem[58880];
    const int t = threadIdx.x;
    const int lane = t & 63;
    const int w = t >> 6;
    const int quad = lane >> 4;
    const int c16 = lane & 15;

    if (blockIdx.x >= 128){
        // ---------------- LSTM branch ----------------
        ushort* hbi = (ushort*)smem;            // [2][16*LHS]
        ushort* hlo = (ushort*)(smem + 4608);
        ushort* xls = (ushort*)(smem + 9216);   // [TT*16*LXS]
        const int m0 = (blockIdx.x - 128) * 16;

        {
            unsigned* h0 = (unsigned*)hbi;
            unsigned* l0 = (unsigned*)hlo;
            for (int i = t; i < 2*16*LHS/2; i += 256){ h0[i] = 0u; l0[i] = 0u; }
            unsigned* xw = (unsigned*)xls;
            for (int i = t; i < TT*16*LXS/2; i += 256) xw[i] = 0u;
        }
        short8 bw[4][2]; short8 bx[4]; float bc[4];
        #pragma unroll
        for (int tt = 0; tt < 4; ++tt){
            const int ng = (w + 4*tt)*16 + c16;
            bc[tt] = bcombG[ng];
            #pragma unroll
            for (int ks = 0; ks < 2; ++ks)
                bw[tt][ks] = *(const short8*)&whhfrag[(((w*4+tt)*2)+ks)*512 + lane*8];
            short8 vx = {0,0,0,0,0,0,0,0};
            if (quad == 0){
                #pragma unroll
                for (int j = 0; j < 8; ++j) vx[j] = (short)f2bu(wcombG[j*256 + ng]);
            }
            bx[tt] = vx;
        }
        __syncthreads();
        for (int i = t; i < 16*TT*NXF; i += 256){
            int r = i / (TT*NXF);
            int rem = i - r*(TT*NXF);
            int st = rem >> 3, f = rem & 7;
            xls[st*(16*LXS) + r*LXS + f] = f2bu(x[(size_t)(m0+r)*(TT*NXF) + rem]);
        }
        __syncthreads();

        float cst[4] = {0,0,0,0};
        float hf[4]  = {0,0,0,0};

        for (int st = 0; st < TT; ++st){
            const int p = st & 1;
            const ushort* hb  = hbi + p*(16*LHS);
            const ushort* hl_ = hlo + p*(16*LHS);
            short8 ahi0 = *(const short8*)&hb[c16*LHS + quad*8];
            short8 ahi1 = *(const short8*)&hb[c16*LHS + 32 + quad*8];
            short8 alo0 = *(const short8*)&hl_[c16*LHS + quad*8];
            short8 alo1 = *(const short8*)&hl_[c16*LHS + 32 + quad*8];
            short8 ax   = *(const short8*)&xls[st*(16*LXS) + c16*LXS + quad*8];
            f32x4 acc[4];
            #pragma unroll
            for (int tt = 0; tt < 4; ++tt){
                f32x4 a = {bc[tt], bc[tt], bc[tt], bc[tt]};
                a = __builtin_amdgcn_mfma_f32_16x16x32_bf16(ax,   bx[tt],    a, 0,0,0);
                a = __builtin_amdgcn_mfma_f32_16x16x32_bf16(ahi0, bw[tt][0], a, 0,0,0);
                a = __builtin_amdgcn_mfma_f32_16x16x32_bf16(ahi1, bw[tt][1], a, 0,0,0);
                a = __builtin_amdgcn_mfma_f32_16x16x32_bf16(alo0, bw[tt][0], a, 0,0,0);
                a = __builtin_amdgcn_mfma_f32_16x16x32_bf16(alo1, bw[tt][1], a, 0,0,0);
                acc[tt] = a;
            }
            ushort* ho   = hbi + (p^1)*(16*LHS);
            ushort* lo_o = hlo + (p^1)*(16*LHS);
            #pragma unroll
            for (int reg = 0; reg < 4; ++reg){
                float gi = acc[0][reg], gf = acc[1][reg], gg = acc[2][reg], go = acc[3][reg];
                float cn = sigm(gf)*cst[reg] + sigm(gi)*tanh_fast(gg);
                cst[reg] = cn;
                float hn = sigm(go)*tanh_fast(cn);
                hf[reg] = hn;
                ushort hu = f2bu(hn);
                float lov = hn - bu2f(hu);
                int addr = (quad*4+reg)*LHS + w*16 + c16;
                ho[addr] = hu;
                lo_o[addr] = f2bu(lov);
            }
            __syncthreads();
        }
        #pragma unroll
        for (int reg = 0; reg < 4; ++reg)
            hl[(size_t)(m0 + quad*4 + reg)*HH + w*16 + c16] = hf[reg];
        return;
    }

    // ---------------- attn layer1 + GAT2-pre branch ----------------
    unsigned (*smask)[16] = (unsigned(*)[16])smem;                 // 1024
    float* er_s  = (float*)(smem + 1024);                          // 2048
    float* sal   = (float*)(smem + 3072);                          // 256
    float* sar   = (float*)(smem + 3328);                          // 256
    float (*alpha)[516] = (float(*)[516])(smem + 3584);            // 33024
    float* uSpace = (float*)(smem + 36608);                        // 17920  (HT then sw2)
    float (*xh2)[68] = (float(*)[68])(smem + 54528);               // 4352

    const int b = blockIdx.x >> 5;
    const int m0 = (blockIdx.x & 31) * 16;
    const int l = lane;
    float (*HT)[70] = (float(*)[70])uSpace;

    if (t < 64) sal[t] = al2[t]; else if (t < 128) sar[t-64] = ar2[t-64];
    ((unsigned*)smask)[t] = 0;
    er_s[t] = er_in[b*NN + t];
    er_s[t+256] = er_in[b*NN + t + 256];
    __syncthreads();
    for (int e = t; e < E; e += 256){
        int s = ei[e];
        unsigned rl = (unsigned)(s - m0);
        if (rl < 16u){
            int d = ei[E + e];
            atomicOr(&smask[rl][d>>5], 1u << (d & 31));
        }
    }
    const float* Hbase = Hbuf + (size_t)b*NN*HH;
    const int nn = t >> 2, cc = t & 3;
    float4 r0,r1,r2,r3;
    {
        const float4* src = (const float4*)(Hbase + (size_t)nn*HH + cc*16);
        r0 = src[0]; r1 = src[1]; r2 = src[2]; r3 = src[3];
    }
    __syncthreads();
    for (int q = 0; q < 4; ++q){
        const int i = w*4 + q;
        const float elv = el_in[b*NN + m0 + i];
        float e8[8]; unsigned mk = 0; float mx = -1e30f;
        #pragma unroll
        for (int j = 0; j < 8; ++j){
            int n = l + 64*j;
            float ev = elv + er_s[n];
            ev = ev >= 0.f ? ev : 0.2f*ev;
            unsigned mb = (smask[i][(l>>5) + 2*j] >> (l & 31)) & 1u;
            e8[j] = ev;
            if (mb){ mk |= (1u<<j); mx = fmaxf(mx, ev); }
        }
        #pragma unroll
        for (int o = 32; o; o >>= 1) mx = fmaxf(mx, __shfl_xor(mx, o));
        float s = 0.f;
        #pragma unroll
        for (int j = 0; j < 8; ++j){
            float p = ((mk>>j) & 1u) ? __expf(e8[j]-mx) : 0.f;
            e8[j] = p; s += p;
        }
        #pragma unroll
        for (int o = 32; o; o >>= 1) s += __shfl_xor(s, o);
        const float inv = 1.f/s;
        #pragma unroll
        for (int j = 0; j < 8; ++j) alpha[i][l + 64*j] = e8[j]*inv;
    }
    __syncthreads();

    f32x4 acc = {0.f,0.f,0.f,0.f};
    for (int tile = 0; tile < 8; ++tile){
        {
            float v[16] = {r0.x,r0.y,r0.z,r0.w, r1.x,r1.y,r1.z,r1.w,
                           r2.x,r2.y,r2.z,r2.w, r3.x,r3.y,r3.z,r3.w};
            #pragma unroll
            for (int jj = 0; jj < 16; ++jj) HT[cc*16 + jj][nn] = v[jj];
        }
        if (tile < 7){
            const float4* src = (const float4*)(Hbase + (size_t)((tile+1)*64 + nn)*HH + cc*16);
            r0 = src[0]; r1 = src[1]; r2 = src[2]; r3 = src[3];
        }
        __syncthreads();
        #pragma unroll
        for (int ks = 0; ks < 2; ++ks){
            const int k0 = tile*64 + ks*32;
            const float* ap = &alpha[c16][k0 + quad*8];
            float4 a0 = *(const float4*)ap;
            float4 a1 = *(const float4*)(ap + 4);
            const float* bp = &HT[w*16 + c16][ks*32 + quad*8];
            float2 b0 = *(const float2*)bp,     b1 = *(const float2*)(bp+2);
            float2 b2 = *(const float2*)(bp+4), b3 = *(const float2*)(bp+6);
            float af[8] = {a0.x,a0.y,a0.z,a0.w,a1.x,a1.y,a1.z,a1.w};
            float bf[8] = {b0.x,b0.y,b1.x,b1.y,b2.x,b2.y,b3.x,b3.y};
            short8 ahi, alo, bhi, blo;
            split8(af, ahi, alo);
            split8(bf, bhi, blo);
            acc = __builtin_amdgcn_mfma_f32_16x16x32_bf16(ahi, bhi, acc, 0,0,0);
            acc = __builtin_amdgcn_mfma_f32_16x16x32_bf16(alo, bhi, acc, 0,0,0);
            acc = __builtin_amdgcn_mfma_f32_16x16x32_bf16(ahi, blo, acc, 0,0,0);
        }
        __syncthreads();
    }
    {
        const int h = w*16 + c16;
        const float bv = bias1[h];
        #pragma unroll
        for (int reg = 0; reg < 4; ++reg)
            xh2[quad*4 + reg][h] = gelu_exact(acc[reg] + bv);
    }
    __syncthreads();
    float* sw2 = uSpace;
    #pragma unroll
    for (int i = 0; i < 16; ++i) sw2[t + 256*i] = W2[t + 256*i];
    __syncthreads();
    {
        const int h = l;
        for (int q = 0; q < 4; ++q){
            const int i = w + 4*q;
            float acc2 = 0.f;
            const float4* xr = (const float4*)&xh2[i][0];
            #pragma unroll
            for (int k4 = 0; k4 < 16; ++k4){
                float4 xv = xr[k4];
                acc2 += xv.x*sw2[(4*k4+0)*HH+h] + xv.y*sw2[(4*k4+1)*HH+h]
                      + xv.z*sw2[(4*k4+2)*HH+h] + xv.w*sw2[(4*k4+3)*HH+h];
            }
            const int m = b*NN + m0 + i;
            H2[(size_t)m*HH + h] = acc2;
            float v1 = acc2*sal[h], v2 = acc2*sar[h];
            #pragma unroll
            for (int o = 32; o; o >>= 1){ v1 += __shfl_xor(v1,o); v2 += __shfl_xor(v2,o); }
            if (h == 0){ el2[m] = v1; er2[m] = v2; }
        }
    }
}

// =============== K3: attn layer2 + LN(g2)+LN(hl) + decode ===============
__global__ __launch_bounds__(256,2) void attn2_final_kernel(
    const float* __restrict__ Hbuf, const float* __restrict__ el_in, const float* __restrict__ er_in,
    const int* __restrict__ ei, int E,
    const float* __restrict__ bias2,
    const float* __restrict__ hl,
    const float* __restrict__ g_l, const float* __restrict__ b_l,
    const float* __restrict__ g_g, const float* __restrict__ b_g,
    const float* __restrict__ W_d, const float* __restrict__ b_d,
    float* __restrict__ out)
{
    __shared__ __align__(16) char smem[54016];
    unsigned (*smask)[16] = (unsigned(*)[16])smem;                 // 1024
    float* er_s  = (float*)(smem + 1024);                          // 2048
    float (*alpha)[516] = (float(*)[516])(smem + 3072);            // 33024
    float* uSpace = (float*)(smem + 36096);                        // 17920

    const int t = threadIdx.x;
    const int b = blockIdx.x >> 5;
    const int m0 = (blockIdx.x & 31) * 16;
    const int l = t & 63, w = t >> 6;
    const int quad = l >> 4, c16 = l & 15;
    float (*HT)[70] = (float(*)[70])uSpace;

    ((unsigned*)smask)[t] = 0;
    er_s[t] = er_in[b*NN + t];
    er_s[t+256] = er_in[b*NN + t + 256];
    __syncthreads();
    for (int e = t; e < E; e += 256){
        int s = ei[e];
        unsigned rl = (unsigned)(s - m0);
        if (rl < 16u){
            int d = ei[E + e];
            atomicOr(&smask[rl][d>>5], 1u << (d & 31));
        }
    }
    const float* Hbase = Hbuf + (size_t)b*NN*HH;
    const int nn = t >> 2, cc = t & 3;
    float4 r0,r1,r2,r3;
    {
        const float4* src = (const float4*)(Hbase + (size_t)nn*HH + cc*16);
        r0 = src[0]; r1 = src[1]; r2 = src[2]; r3 = src[3];
    }
    __syncthreads();
    for (int q = 0; q < 4; ++q){
        const int i = w*4 + q;
        const float elv = el_in[b*NN + m0 + i];
        float e8[8]; unsigned mk = 0; float mx = -1e30f;
        #pragma unroll
        for (int j = 0; j < 8; ++j){
            int n = l + 64*j;
            float ev = elv + er_s[n];
            ev = ev >= 0.f ? ev : 0.2f*ev;
            unsigned mb = (smask[i][(l>>5) + 2*j] >> (l & 31)) & 1u;
            e8[j] = ev;
            if (mb){ mk |= (1u<<j); mx = fmaxf(mx, ev); }
        }
        #pragma unroll
        for (int o = 32; o; o >>= 1) mx = fmaxf(mx, __shfl_xor(mx, o));
        float s = 0.f;
        #pragma unroll
        for (int j = 0; j < 8; ++j){
            float p = ((mk>>j) & 1u) ? __expf(e8[j]-mx) : 0.f;
            e8[j] = p; s += p;
        }
        #pragma unroll
        for (int o = 32; o; o >>= 1) s += __shfl_xor(s, o);
        const float inv = 1.f/s;
        #pragma unroll
        for (int j = 0; j < 8; ++j) alpha[i][l + 64*j] = e8[j]*inv;
    }
    __syncthreads();

    f32x4 acc = {0.f,0.f,0.f,0.f};
    for (int tile = 0; tile < 8; ++tile){
        {
            float v[16] = {r0.x,r0.y,r0.z,r0.w, r1.x,r1.y,r1.z,r1.w,
                           r2.x,r2.y,r2.z,r2.w, r3.x,r3.y,r3.z,r3.w};
            #pragma unroll
            for (int jj = 0; jj < 16; ++jj) HT[cc*16 + jj][nn] = v[jj];
        }
        if (tile < 7){
            const float4* src = (const float4*)(Hbase + (size_t)((tile+1)*64 + nn)*HH + cc*16);
            r0 = src[0]; r1 = src[1]; r2 = src[2]; r3 = src[3];
        }
        __syncthreads();
        #pragma unroll
        for (int ks = 0; ks < 2; ++ks){
            const int k0 = tile*64 + ks*32;
            const float* ap = &alpha[c16][k0 + quad*8];
            float4 a0 = *(const float4*)ap;
            float4 a1 = *(const float4*)(ap + 4);
            const float* bp = &HT[w*16 + c16][ks*32 + quad*8];
            float2 b0 = *(const float2*)bp,     b1 = *(const float2*)(bp+2);
            float2 b2 = *(const float2*)(bp+4), b3 = *(const float2*)(bp+6);
            float af[8] = {a0.x,a0.y,a0.z,a0.w,a1.x,a1.y,a1.z,a1.w};
            float bf[8] = {b0.x,b0.y,b1.x,b1.y,b2.x,b2.y,b3.x,b3.y};
            short8 ahi, alo, bhi, blo;
            split8(af, ahi, alo);
            split8(bf, bhi, blo);
            acc = __builtin_amdgcn_mfma_f32_16x16x32_bf16(ahi, bhi, acc, 0,0,0);
            acc = __builtin_amdgcn_mfma_f32_16x16x32_bf16(alo, bhi, acc, 0,0,0);
            acc = __builtin_amdgcn_mfma_f32_16x16x32_bf16(ahi, blo, acc, 0,0,0);
        }
        __syncthreads();
    }
    // g2 -> LDS (reuse alpha region), then LN+LN+decode
    float* sg2  = (float*)(smem + 3072);
    float* sdec = (float*)(smem + 36096);
    {
        const int h = w*16 + c16;
        const float bv = bias2[h];
        #pragma unroll
        for (int reg = 0; reg < 4; ++reg)
            sg2[(quad*4 + reg)*HH + h] = gelu_exact(acc[reg] + bv);
    }
    __syncthreads();
    const int gbase = b*NN + m0;
    {
        const int h = l;
        for (int q = 0; q < 4; ++q){
            const int ml = w*4 + q;
            float gv = sg2[ml*HH + h];
            float lv = hl[(size_t)(gbase + ml)*HH + h];

            float s1 = gv;
            #pragma unroll
            for (int o = 32; o; o >>= 1) s1 += __shfl_xor(s1, o);
            float dg = gv - s1*(1.f/64.f);
            float v1 = dg*dg;
            #pragma unroll
            for (int o = 32; o; o >>= 1) v1 += __shfl_xor(v1, o);
            float lng = dg*rsqrtf(v1*(1.f/64.f) + 1e-5f)*g_g[h] + b_g[h];

            float s2 = lv;
            #pragma unroll
            for (int o = 32; o; o >>= 1) s2 += __shfl_xor(s2, o);
            float dl = lv - s2*(1.f/64.f);
            float v2 = dl*dl;
            #pragma unroll
            for (int o = 32; o; o >>= 1) v2 += __shfl_xor(v2, o);
            float lnl = dl*rsqrtf(v2*(1.f/64.f) + 1e-5f)*g_l[h] + b_l[h];

            sdec[ml*HH + h] = lng + lnl;
        }
    }
    __syncthreads();
    if (t < 16*PRED){
        int rr = t / PRED, pp = t - rr*PRED;
        float a = b_d[pp];
        #pragma unroll
        for (int k = 0; k < HH; ++k) a += sdec[rr*HH + k]*W_d[k*PRED + pp];
        out[(size_t)(gbase + rr)*PRED + pp] = a;
    }
}

extern "C" void kernel_launch(void* const* d_in, const int* in_sizes, int n_in,
                              void* d_out, int out_size, void* d_ws, size_t ws_size,
                              hipStream_t stream){
    const float* x    = (const float*)d_in[0];
    const int*   ei   = (const int*)  d_in[1];
    const float* Wfc  = (const float*)d_in[2];
    const float* bfc  = (const float*)d_in[3];
    const float* W1   = (const float*)d_in[4];
    const float* al1  = (const float*)d_in[5];
    const float* ar1  = (const float*)d_in[6];
    const float* bias1= (const float*)d_in[7];
    const float* W2   = (const float*)d_in[8];
    const float* al2  = (const float*)d_in[9];
    const float* ar2  = (const float*)d_in[10];
    const float* bias2= (const float*)d_in[11];
    const float* Wih  = (const float*)d_in[12];
    const float* Whh  = (const float*)d_in[13];
    const float* bih  = (const float*)d_in[14];
    const float* bhh  = (const float*)d_in[15];
    const float* g_l  = (const float*)d_in[16];
    const float* b_l  = (const float*)d_in[17];
    const float* g_g  = (const float*)d_in[18];
    const float* b_g  = (const float*)d_in[19];
    const float* W_d  = (const float*)d_in[20];
    const float* b_d  = (const float*)d_in[21];

    float* ws = (float*)d_ws;
    const int E = in_sizes[1] / 2;

    gat1pre_kernel<<<512 + 8, 256, 0, stream>>>(x, Wfc, bfc, W1, al1, ar1,
                                                Wih, Whh, bih, bhh,
                                                ws+WS_HBUF, ws+WS_EL, ws+WS_ER,
                                                ws+WS_WCOMB, ws+WS_BCOMB,
                                                (ushort*)(ws+WS_WHHFRAG));
    mid_fused_kernel<<<256, 256, 0, stream>>>(ws+WS_HBUF, ws+WS_EL, ws+WS_ER,
                                              ei, E, bias1, W2, al2, ar2,
                                              ws+WS_H2, ws+WS_EL2, ws+WS_ER2,
                                              x, ws+WS_WCOMB, ws+WS_BCOMB,
                                              (const ushort*)(ws+WS_WHHFRAG),
                                              ws+WS_HL);
    attn2_final_kernel<<<BB*(NN/16), 256, 0, stream>>>(ws+WS_H2, ws+WS_EL2, ws+WS_ER2,
                                                       ei, E, bias2,
                                                       ws+WS_HL,
                                                       g_l, b_l, g_g, b_g, W_d, b_d,
                                                       (float*)d_out);
}